// Round 6
// baseline (392.227 us; speedup 1.0000x reference)
//
#include <hip/hip_runtime.h>
#include <cstddef>
#include <cstdint>

// Problem constants
static constexpr int M_ROWS  = 32768;   // B*T
static constexpr int D_INK   = 1024;
static constexpr int D_HID   = 512;
static constexpr int D_CODE_ = 256;
static constexpr int N_CODES_= 128;

static constexpr float TAU_GAP = 0.02f;   // ambiguity threshold (error bound ~1e-3 -> 20x margin)

using bf16x8 = __attribute__((ext_vector_type(8))) __bf16;
using f32x4  = __attribute__((ext_vector_type(4))) float;

#define ASM_BAR()   asm volatile("s_barrier" ::: "memory")
#define WAIT_VL0()  asm volatile("s_waitcnt vmcnt(0) lgkmcnt(0)" ::: "memory")
#define WAIT_V0()   asm volatile("s_waitcnt vmcnt(0)" ::: "memory")

// ---------------------------------------------------------------------------
// direct global->LDS DMA, 16 B per lane (dest = wave-uniform base + lane*16)
// ---------------------------------------------------------------------------
__device__ __forceinline__ void dma16(const void* g, void* l) {
    __builtin_amdgcn_global_load_lds(
        (const __attribute__((address_space(1))) void*)g,
        (__attribute__((address_space(3))) void*)l, 16, 0, 0);
}

// stage a [128 rows x 32 k] bf16 hi/lo tile into LDS, frag-linear:
// frag f = kq*128 + rc  holds  src[row0+rc][k0 + kq*8 .. +8]  at elem offset f*8.
__device__ __forceinline__ void stage_pair_dma(const __bf16* __restrict__ hi,
                                               const __bf16* __restrict__ lo,
                                               __bf16* shi, __bf16* slo,
                                               int w, int lane, int row0, int stride, int k0)
{
    #pragma unroll
    for (int ii = 0; ii < 2; ++ii) {
        const int I  = 2 * w + ii;          // 0..7 (wave-uniform)
        const int f  = I * 64 + lane;       // frag 0..511
        const int rc = f & 127;
        const int kq = f >> 7;
        const size_t go = (size_t)(row0 + rc) * stride + k0 + kq * 8;
        dma16(hi + go, shi + (size_t)I * 512);
        dma16(lo + go, slo + (size_t)I * 512);
    }
}

// one BK=32 compute step: 4x4 fragment tile per wave, 3-product hi/lo split
__device__ __forceinline__ void mfma_tile(const __bf16* sAh, const __bf16* sAl,
                                          const __bf16* sBh, const __bf16* sBl,
                                          int wm, int wn, int kq, int lm,
                                          f32x4 (&acc)[4][4])
{
    bf16x8 ah[4], al[4];
    #pragma unroll
    for (int fm = 0; fm < 4; ++fm) {
        const int fA = kq * 128 + wm * 64 + fm * 16 + lm;
        ah[fm] = *(const bf16x8*)(sAh + fA * 8);
        al[fm] = *(const bf16x8*)(sAl + fA * 8);
    }
    #pragma unroll
    for (int fn = 0; fn < 4; ++fn) {
        const int fB = kq * 128 + wn * 64 + fn * 16 + lm;
        const bf16x8 bh = *(const bf16x8*)(sBh + fB * 8);
        const bf16x8 bl = *(const bf16x8*)(sBl + fB * 8);
        #pragma unroll
        for (int fm = 0; fm < 4; ++fm) {
            acc[fm][fn] = __builtin_amdgcn_mfma_f32_16x16x32_bf16(ah[fm], bh, acc[fm][fn], 0, 0, 0);
            acc[fm][fn] = __builtin_amdgcn_mfma_f32_16x16x32_bf16(al[fm], bh, acc[fm][fn], 0, 0, 0);
            acc[fm][fn] = __builtin_amdgcn_mfma_f32_16x16x32_bf16(ah[fm], bl, acc[fm][fn], 0, 0, 0);
        }
    }
}

// ---------------------------------------------------------------------------
// prep: split codebook to hi/lo bf16, per-code norms, zero accumulators.
// ---------------------------------------------------------------------------
__global__ __launch_bounds__(256)
void prep_cb_kernel(const float* __restrict__ cb, __bf16* __restrict__ cbhi,
                    __bf16* __restrict__ cblo, float* __restrict__ cbnorm,
                    float* __restrict__ accum, int* __restrict__ cnt)
{
    const int j = blockIdx.x;
    const int t = threadIdx.x;
    const float v = cb[j * D_CODE_ + t];
    const __bf16 hb = (__bf16)v;
    cbhi[j * D_CODE_ + t] = hb;
    cblo[j * D_CODE_ + t] = (__bf16)(v - (float)hb);

    __shared__ float sr[256];
    sr[t] = v * v;
    __syncthreads();
    for (int s = 128; s >= 1; s >>= 1) {
        if (t < s) sr[t] += sr[t + s];
        __syncthreads();
    }
    if (t == 0) cbnorm[j] = sr[0];
    if (j == 0 && t < 2) accum[t] = 0.0f;
    if (j == 0 && t == 2) *cnt = 0;
}

// ---------------------------------------------------------------------------
// splitT: W [K][N] fp32 -> WT_hi/WT_lo [N][K] bf16, LDS-tiled transpose.
// ---------------------------------------------------------------------------
__global__ __launch_bounds__(256)
void splitT_kernel(const float* __restrict__ W, __bf16* __restrict__ Thi,
                   __bf16* __restrict__ Tlo, int Kd, int Nd)
{
    __shared__ __bf16 sh[64][66];
    __shared__ __bf16 sl[64][66];
    const int t = threadIdx.x;
    const int k0 = blockIdx.x * 64, n0 = blockIdx.y * 64;
    {
        const int nl = t & 63, kr = t >> 6;
        #pragma unroll
        for (int r = 0; r < 16; ++r) {
            const int kl = kr * 16 + r;
            const float v = W[(size_t)(k0 + kl) * Nd + n0 + nl];
            const __bf16 hb = (__bf16)v;
            sh[kl][nl] = hb;
            sl[kl][nl] = (__bf16)(v - (float)hb);
        }
    }
    __syncthreads();
    {
        const int kl = t & 63, nr = t >> 6;
        #pragma unroll
        for (int r = 0; r < 16; ++r) {
            const int nl = nr * 16 + r;
            Thi[(size_t)(n0 + nl) * Kd + k0 + kl] = sh[kl][nl];
            Tlo[(size_t)(n0 + nl) * Kd + k0 + kl] = sl[kl][nl];
        }
    }
}

// ---------------------------------------------------------------------------
// GEMM1: h(hi/lo) = relu(x @ W1 + b1).
// Single-buffered 32KB LDS, 2 raw barriers per K-step (m97 structure),
// 4 blocks/CU for TLP-based latency hiding. Grid: (n fast, m slow) so the
// 4 n-blocks sharing an x panel run concurrently (x fetched ~once from HBM)
// and W1T panels stay L2-resident.
// ---------------------------------------------------------------------------
__global__ __launch_bounds__(256, 4)
void gemm1_kernel(const float* __restrict__ X,
                  const __bf16* __restrict__ BThi, const __bf16* __restrict__ BTlo,
                  const float* __restrict__ bias,
                  __bf16* __restrict__ Chi, __bf16* __restrict__ Clo)
{
    __shared__ __bf16 sAh[4096];   // 8 KB each -> 32 KB total
    __shared__ __bf16 sAl[4096];
    __shared__ __bf16 sBh[4096];
    __shared__ __bf16 sBl[4096];

    const int tid  = threadIdx.x;
    const int lane = tid & 63;
    const int w    = tid >> 6;
    const int wm = w >> 1, wn = w & 1;
    const int kq = lane >> 4, lm = lane & 15;
    const int n0 = blockIdx.x * 128, m0 = blockIdx.y * 128;

    f32x4 acc[4][4] = {};

    // A-frag ownership: f0 = tid (kq 0/1), f1 = tid + 256 (kq 2/3); same row.
    const int f0 = tid, f1 = tid + 256;
    const float* xp = X + (size_t)(m0 + (tid & 127)) * D_INK + (tid >> 7) * 8;

    constexpr int NSTEP = D_INK / 32;
    for (int t = 0; t < NSTEP; ++t) {
        const int k0 = t * 32;
        ASM_BAR();                         // buffer free (prev step's reads done)
        // stage B via DMA
        stage_pair_dma(BThi, BTlo, sBh, sBl, w, lane, n0, D_INK, k0);
        // stage A: load fp32, convert to hi/lo, ds_write
        float v0[8], v1[8];
        *(float4*)&v0[0] = *(const float4*)(xp + k0);
        *(float4*)&v0[4] = *(const float4*)(xp + k0 + 4);
        *(float4*)&v1[0] = *(const float4*)(xp + k0 + 16);
        *(float4*)&v1[4] = *(const float4*)(xp + k0 + 20);
        bf16x8 h8, l8;
        #pragma unroll
        for (int j = 0; j < 8; ++j) {
            const __bf16 hb = (__bf16)v0[j];
            h8[j] = hb; l8[j] = (__bf16)(v0[j] - (float)hb);
        }
        *(bf16x8*)(sAh + f0 * 8) = h8;  *(bf16x8*)(sAl + f0 * 8) = l8;
        #pragma unroll
        for (int j = 0; j < 8; ++j) {
            const __bf16 hb = (__bf16)v1[j];
            h8[j] = hb; l8[j] = (__bf16)(v1[j] - (float)hb);
        }
        *(bf16x8*)(sAh + f1 * 8) = h8;  *(bf16x8*)(sAl + f1 * 8) = l8;
        WAIT_VL0();                        // DMA + ds_writes drained
        ASM_BAR();                         // staged data visible to all waves
        mfma_tile(sAh, sAl, sBh, sBl, wm, wn, kq, lm, acc);
    }

    // epilogue: relu + hi/lo split store (C/D: col = lane&15, row = kq*4 + r)
    #pragma unroll
    for (int fn = 0; fn < 4; ++fn) {
        const int col = n0 + wn * 64 + fn * 16 + lm;
        const float bv = bias[col];
        #pragma unroll
        for (int fm = 0; fm < 4; ++fm) {
            #pragma unroll
            for (int r = 0; r < 4; ++r) {
                const int row = m0 + wm * 64 + fm * 16 + kq * 4 + r;
                const float v = fmaxf(acc[fm][fn][r] + bv, 0.0f);
                const __bf16 hb = (__bf16)v;
                Chi[(size_t)row * D_HID + col] = hb;
                Clo[(size_t)row * D_HID + col] = (__bf16)(v - (float)hb);
            }
        }
    }
}

// ---------------------------------------------------------------------------
// GEMM2: enc(hi/lo) = h @ W2 + b2, plus sum(enc^2) atomic.
// All-DMA staging, single buffer, 2 barriers/step, 4 blocks/CU.
// ---------------------------------------------------------------------------
__global__ __launch_bounds__(256, 4)
void gemm2_kernel(const __bf16* __restrict__ Ahi, const __bf16* __restrict__ Alo,
                  const __bf16* __restrict__ BThi, const __bf16* __restrict__ BTlo,
                  const float* __restrict__ bias,
                  __bf16* __restrict__ Chi, __bf16* __restrict__ Clo,
                  float* __restrict__ accum)
{
    __shared__ __bf16 sAh[4096];
    __shared__ __bf16 sAl[4096];
    __shared__ __bf16 sBh[4096];
    __shared__ __bf16 sBl[4096];

    const int tid  = threadIdx.x;
    const int lane = tid & 63;
    const int w    = tid >> 6;
    const int wm = w >> 1, wn = w & 1;
    const int kq = lane >> 4, lm = lane & 15;
    const int n0 = blockIdx.x * 128, m0 = blockIdx.y * 128;

    f32x4 acc[4][4] = {};

    constexpr int NSTEP = D_HID / 32;
    for (int t = 0; t < NSTEP; ++t) {
        const int k0 = t * 32;
        ASM_BAR();
        stage_pair_dma(Ahi, Alo, sAh, sAl, w, lane, m0, D_HID, k0);
        stage_pair_dma(BThi, BTlo, sBh, sBl, w, lane, n0, D_HID, k0);
        WAIT_V0();
        ASM_BAR();
        mfma_tile(sAh, sAl, sBh, sBl, wm, wn, kq, lm, acc);
    }

    float sumsq = 0.0f;
    #pragma unroll
    for (int fn = 0; fn < 4; ++fn) {
        const int col = n0 + wn * 64 + fn * 16 + lm;
        const float bv = bias[col];
        #pragma unroll
        for (int fm = 0; fm < 4; ++fm) {
            #pragma unroll
            for (int r = 0; r < 4; ++r) {
                const int row = m0 + wm * 64 + fm * 16 + kq * 4 + r;
                const float v = acc[fm][fn][r] + bv;
                sumsq = fmaf(v, v, sumsq);
                const __bf16 hb = (__bf16)v;
                Chi[(size_t)row * D_CODE_ + col] = hb;
                Clo[(size_t)row * D_CODE_ + col] = (__bf16)(v - (float)hb);
            }
        }
    }
    #pragma unroll
    for (int mk = 1; mk <= 32; mk <<= 1) sumsq += __shfl_xor(sumsq, mk);
    if (lane == 0) atomicAdd(&accum[1], sumsq);
}

// ---------------------------------------------------------------------------
// dist: dots = enc @ cb^T via MFMA (one n-block = all 128 codes);
// epilogue argmin + gap flagging + loss sum.
// ---------------------------------------------------------------------------
__global__ __launch_bounds__(256, 4)
void dist_kernel(const __bf16* __restrict__ Ehi, const __bf16* __restrict__ Elo,
                 const __bf16* __restrict__ CBhi, const __bf16* __restrict__ CBlo,
                 const float* __restrict__ cbn,
                 float* __restrict__ outIdx, float* __restrict__ accum,
                 int* __restrict__ cnt, int* __restrict__ list)
{
    __shared__ __bf16 sAh[4096];
    __shared__ __bf16 sAl[4096];
    __shared__ __bf16 sBh[4096];
    __shared__ __bf16 sBl[4096];

    const int tid  = threadIdx.x;
    const int lane = tid & 63;
    const int w    = tid >> 6;
    const int wm = w >> 1, wn = w & 1;
    const int kq = lane >> 4, lm = lane & 15;
    const int m0 = blockIdx.x * 128;

    float cbn_l[4];
    #pragma unroll
    for (int fn = 0; fn < 4; ++fn) cbn_l[fn] = cbn[wn * 64 + fn * 16 + lm];

    f32x4 acc[4][4] = {};

    constexpr int NSTEP = D_CODE_ / 32;
    for (int t = 0; t < NSTEP; ++t) {
        const int k0 = t * 32;
        ASM_BAR();
        stage_pair_dma(Ehi, Elo, sAh, sAl, w, lane, m0, D_CODE_, k0);
        stage_pair_dma(CBhi, CBlo, sBh, sBl, w, lane, 0, D_CODE_, k0);
        WAIT_V0();
        ASM_BAR();
        mfma_tile(sAh, sAl, sBh, sBl, wm, wn, kq, lm, acc);
    }

    __syncthreads();   // full drain before LDS reuse as epilogue scratch
    float* eb1 = (float*)sAh;        // [2][128]
    float* eb2 = eb1 + 256;
    int*   eix = (int*)(eb2 + 256);

    #pragma unroll
    for (int fm = 0; fm < 4; ++fm) {
        #pragma unroll
        for (int r = 0; r < 4; ++r) {
            float b1v = 3.4e38f, b2v = 3.4e38f; int bi = 0;
            #pragma unroll
            for (int fn = 0; fn < 4; ++fn) {
                const float v = fmaf(-2.0f, acc[fm][fn][r], cbn_l[fn]);
                if (v < b1v) { b2v = b1v; b1v = v; bi = wn * 64 + fn * 16 + lm; }
                else if (v < b2v) b2v = v;
            }
            #pragma unroll
            for (int mk = 1; mk <= 8; mk <<= 1) {
                const float o1 = __shfl_xor(b1v, mk);
                const float o2 = __shfl_xor(b2v, mk);
                const int   oi = __shfl_xor(bi,  mk);
                if (o1 < b1v || (o1 == b1v && oi < bi)) { b2v = fminf(b1v, o2); b1v = o1; bi = oi; }
                else b2v = fminf(b2v, o1);
            }
            const int rl = wm * 64 + fm * 16 + kq * 4 + r;
            if (lm == 0) { eb1[wn * 128 + rl] = b1v; eb2[wn * 128 + rl] = b2v; eix[wn * 128 + rl] = bi; }
        }
    }
    __syncthreads();

    if (tid < 128) {
        const int rl = tid;
        const float a1 = eb1[rl], a2 = eb2[rl]; const int ai = eix[rl];
        const float o1 = eb1[128 + rl], o2 = eb2[128 + rl]; const int oi = eix[128 + rl];
        float B1, B2; int BI;
        if (o1 < a1 || (o1 == a1 && oi < ai)) { B1 = o1; BI = oi; B2 = fminf(a1, o2); }
        else                                  { B1 = a1; BI = ai; B2 = fminf(a2, o1); }
        outIdx[m0 + rl] = (float)BI;
        if (B2 - B1 < TAU_GAP) { const int p = atomicAdd(cnt, 1); list[p] = m0 + rl; }
        float s = B1;
        #pragma unroll
        for (int mk = 1; mk <= 32; mk <<= 1) s += __shfl_xor(s, mk);
        if (lane == 0) atomicAdd(&accum[0], s);
    }
}

// ---------------------------------------------------------------------------
// fixup: exact fp32 recompute of flagged (near-tie) rows; overwrite index.
// ---------------------------------------------------------------------------
__global__ __launch_bounds__(256)
void fixup_kernel(const float* __restrict__ x, const float* __restrict__ W1,
                  const float* __restrict__ b1, const float* __restrict__ W2,
                  const float* __restrict__ b2, const float* __restrict__ cb,
                  const float* __restrict__ cbnorm,
                  const int* __restrict__ cnt, const int* __restrict__ list,
                  float* __restrict__ outIdx)
{
    __shared__ float xr[1024];
    __shared__ float hr[512];
    __shared__ float er[256];
    __shared__ float dv[128];
    __shared__ int   di[128];

    const int tid = threadIdx.x;
    const int n = *cnt;
    for (int it = blockIdx.x; it < n; it += gridDim.x) {
        const int row = list[it];
        __syncthreads();
        #pragma unroll
        for (int i = 0; i < 4; ++i)
            xr[tid + i * 256] = x[(size_t)row * D_INK + tid + i * 256];
        __syncthreads();
        {
            const int c = tid * 2;
            float s0a = 0.f, s0b = 0.f, s1a = 0.f, s1b = 0.f;
            #pragma unroll 4
            for (int k = 0; k < D_INK; k += 2) {
                const float xv0 = xr[k], xv1 = xr[k + 1];
                const float2 w0 = *(const float2*)(W1 + (size_t)k * D_HID + c);
                const float2 w1 = *(const float2*)(W1 + (size_t)(k + 1) * D_HID + c);
                s0a = fmaf(xv0, w0.x, s0a); s1a = fmaf(xv0, w0.y, s1a);
                s0b = fmaf(xv1, w1.x, s0b); s1b = fmaf(xv1, w1.y, s1b);
            }
            hr[c]     = fmaxf(s0a + s0b + b1[c], 0.f);
            hr[c + 1] = fmaxf(s1a + s1b + b1[c + 1], 0.f);
        }
        __syncthreads();
        {
            float sa = 0.f, sb = 0.f;
            #pragma unroll 4
            for (int k = 0; k < D_HID; k += 2) {
                sa = fmaf(hr[k],     W2[(size_t)k * D_CODE_ + tid],       sa);
                sb = fmaf(hr[k + 1], W2[(size_t)(k + 1) * D_CODE_ + tid], sb);
            }
            er[tid] = sa + sb + b2[tid];
        }
        __syncthreads();
        if (tid < 128) {
            float e2a = 0.f, e2b = 0.f, da = 0.f, db = 0.f;
            const float* cr = cb + (size_t)tid * D_CODE_;
            #pragma unroll 4
            for (int k = 0; k < D_CODE_; k += 2) {
                e2a = fmaf(er[k], er[k], e2a);         e2b = fmaf(er[k + 1], er[k + 1], e2b);
                da  = fmaf(er[k], cr[k], da);          db  = fmaf(er[k + 1], cr[k + 1], db);
            }
            dv[tid] = ((e2a + e2b) - 2.0f * (da + db)) + cbnorm[tid];
            di[tid] = tid;
        }
        __syncthreads();
        for (int st = 64; st >= 1; st >>= 1) {
            if (tid < st) {
                const float a = dv[tid], b = dv[tid + st];
                const int  ib = di[tid + st];
                if (b < a || (b == a && ib < di[tid])) { dv[tid] = b; di[tid] = ib; }
            }
            __syncthreads();
        }
        if (tid == 0) outIdx[row] = (float)di[0];
    }
}

// ---------------------------------------------------------------------------
__global__ void finalize_kernel(const float* __restrict__ accum, float* __restrict__ out)
{
    const float inv = 1.0f / (32768.0f * 256.0f);
    const float loss = (accum[0] + accum[1]) * inv;   // commitment == codebook
    out[32768] = loss;
    out[32769] = loss;
    out[32770] = 1.25f * loss;
}

// ---------------------------------------------------------------------------
extern "C" void kernel_launch(void* const* d_in, const int* in_sizes, int n_in,
                              void* d_out, int out_size, void* d_ws, size_t ws_size,
                              hipStream_t stream)
{
    (void)in_sizes; (void)n_in; (void)out_size; (void)ws_size;

    const float* x  = (const float*)d_in[0];  // [32768,1024]
    const float* W1 = (const float*)d_in[1];  // [1024,512]
    const float* b1 = (const float*)d_in[2];  // [512]
    const float* W2 = (const float*)d_in[3];  // [512,256]
    const float* b2 = (const float*)d_in[4];  // [256]
    const float* cb = (const float*)d_in[5];  // [128,256]
    float* out = (float*)d_out;

    // workspace layout (bytes)
    char* ws = (char*)d_ws;
    __bf16* W1Thi = (__bf16*)(ws + 0);                    // 1 MB  [512][1024]
    __bf16* W1Tlo = (__bf16*)(ws + (1u<<20));             // 1 MB
    __bf16* W2Thi = (__bf16*)(ws + (2u<<20));             // 256 KB [256][512]
    __bf16* W2Tlo = (__bf16*)(ws + (2u<<20) + 262144);    // 256 KB
    __bf16* cbhi  = (__bf16*)(ws + (2u<<20) + 524288);    // 64 KB  [128][256]
    __bf16* cblo  = (__bf16*)(ws + (2u<<20) + 589824);    // 64 KB
    float*  cbn   = (float* )(ws + (2u<<20) + 655360);    // 512 B
    float*  accum = (float* )(ws + (2u<<20) + 655872);    // 64 B
    int*    cnt   = (int*   )(ws + (2u<<20) + 655936);    // 64 B
    int*    list  = (int*   )(ws + (2u<<20) + 656000);    // 128 KB
    __bf16* h_hi  = (__bf16*)(ws + (size_t)(4u<<20));             // 32 MB
    __bf16* h_lo  = (__bf16*)(ws + (size_t)(4u<<20) + 33554432);  // 32 MB
    __bf16* enchi = (__bf16*)(ws + (size_t)(4u<<20) + 67108864);  // 16 MB
    __bf16* enclo = (__bf16*)(ws + (size_t)(4u<<20) + 83886080);  // 16 MB

    prep_cb_kernel<<<N_CODES_, 256, 0, stream>>>(cb, cbhi, cblo, cbn, accum, cnt);
    splitT_kernel<<<dim3(D_INK / 64, D_HID / 64), 256, 0, stream>>>(W1, W1Thi, W1Tlo, D_INK, D_HID);
    splitT_kernel<<<dim3(D_HID / 64, D_CODE_ / 64), 256, 0, stream>>>(W2, W2Thi, W2Tlo, D_HID, D_CODE_);

    // grids are (n fast, m slow) for input-panel L2/L3 reuse
    gemm1_kernel<<<dim3(D_HID / 128, M_ROWS / 128), 256, 0, stream>>>(
        x, W1Thi, W1Tlo, b1, h_hi, h_lo);
    gemm2_kernel<<<dim3(D_CODE_ / 128, M_ROWS / 128), 256, 0, stream>>>(
        h_hi, h_lo, W2Thi, W2Tlo, b2, enchi, enclo, accum);
    dist_kernel<<<M_ROWS / 128, 256, 0, stream>>>(
        enchi, enclo, cbhi, cblo, cbn, out, accum, cnt, list);
    fixup_kernel<<<256, 256, 0, stream>>>(x, W1, b1, W2, b2, cb, cbn, cnt, list, out);
    finalize_kernel<<<1, 1, 0, stream>>>(accum, out);
}

// Round 7
// 314.194 us; speedup vs baseline: 1.2484x; 1.2484x over previous
//
#include <hip/hip_runtime.h>
#include <cstddef>
#include <cstdint>

// Problem constants
static constexpr int M_ROWS  = 32768;   // B*T
static constexpr int D_INK   = 1024;
static constexpr int D_HID   = 512;
static constexpr int D_CODE_ = 256;
static constexpr int N_CODES_= 128;

// fp16 single-product pairwise-d2 jitter sigma ~= 0.019  ->  TAU = 10 sigma
static constexpr float TAU_GAP = 0.20f;

using f16x8 = __attribute__((ext_vector_type(8))) _Float16;
using f32x4 = __attribute__((ext_vector_type(4))) float;

// ---------------------------------------------------------------------------
// direct global->LDS DMA, 16 B per lane (dest = wave-uniform base + lane*16)
// ---------------------------------------------------------------------------
__device__ __forceinline__ void dma16(const void* g, void* l) {
    __builtin_amdgcn_global_load_lds(
        (const __attribute__((address_space(1))) void*)g,
        (__attribute__((address_space(3))) void*)l, 16, 0, 0);
}

// stage a [128 rows x 32 k] fp16 tile into LDS, frag-linear:
// frag f = kq*128 + rc holds src[row0+rc][k0 + kq*8 .. +8] at elem offset f*8.
__device__ __forceinline__ void stage_dma(const _Float16* __restrict__ src,
                                          _Float16* dst,
                                          int w, int lane, int row0, int stride, int k0)
{
    #pragma unroll
    for (int ii = 0; ii < 2; ++ii) {
        const int I  = 2 * w + ii;          // 0..7 (wave-uniform)
        const int f  = I * 64 + lane;       // frag 0..511
        const int rc = f & 127;
        const int kq = f >> 7;
        dma16(src + (size_t)(row0 + rc) * stride + k0 + kq * 8,
              dst + (size_t)I * 512);
    }
}

// one BK=32 compute step: 4x4 fragment tile per wave, single fp16 product
__device__ __forceinline__ void mfma_tile(const _Float16* sA, const _Float16* sB,
                                          int wm, int wn, int kq, int lm,
                                          f32x4 (&acc)[4][4])
{
    f16x8 a[4];
    #pragma unroll
    for (int fm = 0; fm < 4; ++fm)
        a[fm] = *(const f16x8*)(sA + (kq * 128 + wm * 64 + fm * 16 + lm) * 8);
    #pragma unroll
    for (int fn = 0; fn < 4; ++fn) {
        const f16x8 b = *(const f16x8*)(sB + (kq * 128 + wn * 64 + fn * 16 + lm) * 8);
        #pragma unroll
        for (int fm = 0; fm < 4; ++fm)
            acc[fm][fn] = __builtin_amdgcn_mfma_f32_16x16x32_f16(a[fm], b, acc[fm][fn], 0, 0, 0);
    }
}

// bijective XCD swizzle (nwg % 8 == 0): consecutive logical ids -> same XCD L2
__device__ __forceinline__ int xcd_swz(int bid, int nwg) {
    const int q = nwg >> 3;
    return (bid & 7) * q + (bid >> 3);
}

// ---------------------------------------------------------------------------
// prep: codebook -> fp16, exact per-code norms, zero accumulators.
// ---------------------------------------------------------------------------
__global__ __launch_bounds__(256)
void prep_cb_kernel(const float* __restrict__ cb, _Float16* __restrict__ cb16,
                    float* __restrict__ cbnorm, float* __restrict__ accum,
                    int* __restrict__ cnt)
{
    const int j = blockIdx.x;
    const int t = threadIdx.x;
    const float v = cb[j * D_CODE_ + t];
    cb16[j * D_CODE_ + t] = (_Float16)v;

    __shared__ float sr[256];
    sr[t] = v * v;
    __syncthreads();
    for (int s = 128; s >= 1; s >>= 1) {
        if (t < s) sr[t] += sr[t + s];
        __syncthreads();
    }
    if (t == 0) cbnorm[j] = sr[0];
    if (j == 0 && t < 2) accum[t] = 0.0f;
    if (j == 0 && t == 2) *cnt = 0;
}

// ---------------------------------------------------------------------------
// splitT: W [K][N] fp32 -> WT [N][K] fp16, LDS-tiled transpose.
// ---------------------------------------------------------------------------
__global__ __launch_bounds__(256)
void splitT_kernel(const float* __restrict__ W, _Float16* __restrict__ T,
                   int Kd, int Nd)
{
    __shared__ _Float16 sh[64][66];
    const int t = threadIdx.x;
    const int k0 = blockIdx.x * 64, n0 = blockIdx.y * 64;
    {
        const int nl = t & 63, kr = t >> 6;
        #pragma unroll
        for (int r = 0; r < 16; ++r) {
            const int kl = kr * 16 + r;
            sh[kl][nl] = (_Float16)W[(size_t)(k0 + kl) * Nd + n0 + nl];
        }
    }
    __syncthreads();
    {
        const int kl = t & 63, nr = t >> 6;
        #pragma unroll
        for (int r = 0; r < 16; ++r) {
            const int nl = nr * 16 + r;
            T[(size_t)(n0 + nl) * Kd + k0 + kl] = sh[kl][nl];
        }
    }
}

// ---------------------------------------------------------------------------
// GEMM1: h(fp16) = relu(x @ W1 + b1).  A: fp32 -> fp16 in-register, ds_write;
// B: fp16 via global_load_lds.  Double-buffered LDS (32 KB), one
// __syncthreads per K-step, 4 blocks/CU, XCD-swizzled n-fast grid.
// ---------------------------------------------------------------------------
__global__ __launch_bounds__(256, 4)
void gemm1_kernel(const float* __restrict__ X,
                  const _Float16* __restrict__ BT,
                  const float* __restrict__ bias,
                  _Float16* __restrict__ C)
{
    __shared__ _Float16 lds[2][2][4096];   // [buf][A,B][frag elems]  32 KB

    const int tid  = threadIdx.x;
    const int lane = tid & 63;
    const int w    = tid >> 6;
    const int wm = w >> 1, wn = w & 1;
    const int kq = lane >> 4, lm = lane & 15;

    const int swz = xcd_swz(blockIdx.x, (M_ROWS / 128) * (D_HID / 128));
    const int n0 = (swz & 3) * 128;           // D_HID/128 = 4, n fast
    const int m0 = (swz >> 2) * 128;

    f32x4 acc[4][4] = {};

    // A-frag ownership: f0 = tid (kq 0/1), f1 = tid + 256 (kq 2/3); same row.
    const int f0 = tid, f1 = tid + 256;
    const float* xp = X + (size_t)(m0 + (tid & 127)) * D_INK + (tid >> 7) * 8;

    // prologue: stage step 0 into buf 0
    {
        stage_dma(BT, &lds[0][1][0], w, lane, n0, D_INK, 0);
        float v0[8], v1[8];
        *(float4*)&v0[0] = *(const float4*)(xp);
        *(float4*)&v0[4] = *(const float4*)(xp + 4);
        *(float4*)&v1[0] = *(const float4*)(xp + 16);
        *(float4*)&v1[4] = *(const float4*)(xp + 20);
        f16x8 h8;
        #pragma unroll
        for (int j = 0; j < 8; ++j) h8[j] = (_Float16)v0[j];
        *(f16x8*)(&lds[0][0][0] + f0 * 8) = h8;
        #pragma unroll
        for (int j = 0; j < 8; ++j) h8[j] = (_Float16)v1[j];
        *(f16x8*)(&lds[0][0][0] + f1 * 8) = h8;
    }

    constexpr int NSTEP = D_INK / 32;
    for (int t = 0; t < NSTEP; ++t) {
        const int cur = t & 1, nxt = cur ^ 1;
        __syncthreads();               // buf[cur] staged & visible, buf[nxt] free
        if (t + 1 < NSTEP) {
            const int k0n = (t + 1) * 32;
            stage_dma(BT, &lds[nxt][1][0], w, lane, n0, D_INK, k0n);
            float v0[8], v1[8];
            *(float4*)&v0[0] = *(const float4*)(xp + k0n);
            *(float4*)&v0[4] = *(const float4*)(xp + k0n + 4);
            *(float4*)&v1[0] = *(const float4*)(xp + k0n + 16);
            *(float4*)&v1[4] = *(const float4*)(xp + k0n + 20);
            f16x8 h8;
            #pragma unroll
            for (int j = 0; j < 8; ++j) h8[j] = (_Float16)v0[j];
            *(f16x8*)(&lds[nxt][0][0] + f0 * 8) = h8;
            #pragma unroll
            for (int j = 0; j < 8; ++j) h8[j] = (_Float16)v1[j];
            *(f16x8*)(&lds[nxt][0][0] + f1 * 8) = h8;
        }
        mfma_tile(&lds[cur][0][0], &lds[cur][1][0], wm, wn, kq, lm, acc);
    }

    // epilogue: relu + fp16 store (C/D: col = lane&15, row = kq*4 + r)
    #pragma unroll
    for (int fn = 0; fn < 4; ++fn) {
        const int col = n0 + wn * 64 + fn * 16 + lm;
        const float bv = bias[col];
        #pragma unroll
        for (int fm = 0; fm < 4; ++fm) {
            #pragma unroll
            for (int r = 0; r < 4; ++r) {
                const int row = m0 + wm * 64 + fm * 16 + kq * 4 + r;
                C[(size_t)row * D_HID + col] = (_Float16)fmaxf(acc[fm][fn][r] + bv, 0.0f);
            }
        }
    }
}

// ---------------------------------------------------------------------------
// GEMM2: enc(fp16) = h @ W2 + b2, plus sum(enc^2) atomic.  All-DMA staging.
// ---------------------------------------------------------------------------
__global__ __launch_bounds__(256, 4)
void gemm2_kernel(const _Float16* __restrict__ A, const _Float16* __restrict__ BT,
                  const float* __restrict__ bias, _Float16* __restrict__ C,
                  float* __restrict__ accum)
{
    __shared__ _Float16 lds[2][2][4096];

    const int tid  = threadIdx.x;
    const int lane = tid & 63;
    const int w    = tid >> 6;
    const int wm = w >> 1, wn = w & 1;
    const int kq = lane >> 4, lm = lane & 15;

    const int swz = xcd_swz(blockIdx.x, (M_ROWS / 128) * (D_CODE_ / 128));
    const int n0 = (swz & 1) * 128;           // D_CODE_/128 = 2, n fast
    const int m0 = (swz >> 1) * 128;

    f32x4 acc[4][4] = {};

    stage_dma(A,  &lds[0][0][0], w, lane, m0, D_HID, 0);
    stage_dma(BT, &lds[0][1][0], w, lane, n0, D_HID, 0);

    constexpr int NSTEP = D_HID / 32;
    for (int t = 0; t < NSTEP; ++t) {
        const int cur = t & 1, nxt = cur ^ 1;
        __syncthreads();
        if (t + 1 < NSTEP) {
            const int k0n = (t + 1) * 32;
            stage_dma(A,  &lds[nxt][0][0], w, lane, m0, D_HID, k0n);
            stage_dma(BT, &lds[nxt][1][0], w, lane, n0, D_HID, k0n);
        }
        mfma_tile(&lds[cur][0][0], &lds[cur][1][0], wm, wn, kq, lm, acc);
    }

    float sumsq = 0.0f;
    #pragma unroll
    for (int fn = 0; fn < 4; ++fn) {
        const int col = n0 + wn * 64 + fn * 16 + lm;
        const float bv = bias[col];
        #pragma unroll
        for (int fm = 0; fm < 4; ++fm) {
            #pragma unroll
            for (int r = 0; r < 4; ++r) {
                const int row = m0 + wm * 64 + fm * 16 + kq * 4 + r;
                const float v = acc[fm][fn][r] + bv;
                sumsq = fmaf(v, v, sumsq);
                C[(size_t)row * D_CODE_ + col] = (_Float16)v;
            }
        }
    }
    #pragma unroll
    for (int mk = 1; mk <= 32; mk <<= 1) sumsq += __shfl_xor(sumsq, mk);
    if (lane == 0) atomicAdd(&accum[1], sumsq);
}

// ---------------------------------------------------------------------------
// dist: dots = enc @ cb^T via MFMA (one n-block = all 128 codes);
// epilogue argmin + second-best gap flagging + min-term loss sum.
// ---------------------------------------------------------------------------
__global__ __launch_bounds__(256, 4)
void dist_kernel(const _Float16* __restrict__ E, const _Float16* __restrict__ CB,
                 const float* __restrict__ cbn,
                 float* __restrict__ outIdx, float* __restrict__ accum,
                 int* __restrict__ cnt, int* __restrict__ list)
{
    __shared__ _Float16 lds[2][2][4096];

    const int tid  = threadIdx.x;
    const int lane = tid & 63;
    const int w    = tid >> 6;
    const int wm = w >> 1, wn = w & 1;
    const int kq = lane >> 4, lm = lane & 15;
    const int m0 = blockIdx.x * 128;

    float cbn_l[4];
    #pragma unroll
    for (int fn = 0; fn < 4; ++fn) cbn_l[fn] = cbn[wn * 64 + fn * 16 + lm];

    f32x4 acc[4][4] = {};

    stage_dma(E,  &lds[0][0][0], w, lane, m0, D_CODE_, 0);
    stage_dma(CB, &lds[0][1][0], w, lane, 0, D_CODE_, 0);

    constexpr int NSTEP = D_CODE_ / 32;
    for (int t = 0; t < NSTEP; ++t) {
        const int cur = t & 1, nxt = cur ^ 1;
        __syncthreads();
        if (t + 1 < NSTEP) {
            const int k0n = (t + 1) * 32;
            stage_dma(E,  &lds[nxt][0][0], w, lane, m0, D_CODE_, k0n);
            stage_dma(CB, &lds[nxt][1][0], w, lane, 0, D_CODE_, k0n);
        }
        mfma_tile(&lds[cur][0][0], &lds[cur][1][0], wm, wn, kq, lm, acc);
    }

    __syncthreads();   // all LDS reads done before reuse as epilogue scratch
    float* eb1 = (float*)&lds[0][0][0];        // [2][128]
    float* eb2 = eb1 + 256;
    int*   eix = (int*)(eb2 + 256);

    #pragma unroll
    for (int fm = 0; fm < 4; ++fm) {
        #pragma unroll
        for (int r = 0; r < 4; ++r) {
            float b1v = 3.4e38f, b2v = 3.4e38f; int bi = 0;
            #pragma unroll
            for (int fn = 0; fn < 4; ++fn) {
                const float v = fmaf(-2.0f, acc[fm][fn][r], cbn_l[fn]);
                if (v < b1v) { b2v = b1v; b1v = v; bi = wn * 64 + fn * 16 + lm; }
                else if (v < b2v) b2v = v;
            }
            #pragma unroll
            for (int mk = 1; mk <= 8; mk <<= 1) {
                const float o1 = __shfl_xor(b1v, mk);
                const float o2 = __shfl_xor(b2v, mk);
                const int   oi = __shfl_xor(bi,  mk);
                if (o1 < b1v || (o1 == b1v && oi < bi)) { b2v = fminf(b1v, o2); b1v = o1; bi = oi; }
                else b2v = fminf(b2v, o1);
            }
            const int rl = wm * 64 + fm * 16 + kq * 4 + r;
            if (lm == 0) { eb1[wn * 128 + rl] = b1v; eb2[wn * 128 + rl] = b2v; eix[wn * 128 + rl] = bi; }
        }
    }
    __syncthreads();

    if (tid < 128) {
        const int rl = tid;
        const float a1 = eb1[rl], a2 = eb2[rl]; const int ai = eix[rl];
        const float o1 = eb1[128 + rl], o2 = eb2[128 + rl]; const int oi = eix[128 + rl];
        float B1, B2; int BI;
        if (o1 < a1 || (o1 == a1 && oi < ai)) { B1 = o1; BI = oi; B2 = fminf(a1, o2); }
        else                                  { B1 = a1; BI = ai; B2 = fminf(a2, o1); }
        outIdx[m0 + rl] = (float)BI;
        if (B2 - B1 < TAU_GAP) { const int p = atomicAdd(cnt, 1); list[p] = m0 + rl; }
        float s = B1;
        #pragma unroll
        for (int mk = 1; mk <= 32; mk <<= 1) s += __shfl_xor(s, mk);
        if (lane == 0) atomicAdd(&accum[0], s);
    }
}

// ---------------------------------------------------------------------------
// fixup: exact fp32 recompute of flagged (near-tie) rows; overwrite index.
// ---------------------------------------------------------------------------
__global__ __launch_bounds__(256)
void fixup_kernel(const float* __restrict__ x, const float* __restrict__ W1,
                  const float* __restrict__ b1, const float* __restrict__ W2,
                  const float* __restrict__ b2, const float* __restrict__ cb,
                  const float* __restrict__ cbnorm,
                  const int* __restrict__ cnt, const int* __restrict__ list,
                  float* __restrict__ outIdx)
{
    __shared__ float xr[1024];
    __shared__ float hr[512];
    __shared__ float er[256];
    __shared__ float dv[128];
    __shared__ int   di[128];

    const int tid = threadIdx.x;
    const int n = *cnt;
    for (int it = blockIdx.x; it < n; it += gridDim.x) {
        const int row = list[it];
        __syncthreads();
        #pragma unroll
        for (int i = 0; i < 4; ++i)
            xr[tid + i * 256] = x[(size_t)row * D_INK + tid + i * 256];
        __syncthreads();
        {
            const int c = tid * 2;
            float s0a = 0.f, s0b = 0.f, s1a = 0.f, s1b = 0.f;
            #pragma unroll 4
            for (int k = 0; k < D_INK; k += 2) {
                const float xv0 = xr[k], xv1 = xr[k + 1];
                const float2 w0 = *(const float2*)(W1 + (size_t)k * D_HID + c);
                const float2 w1 = *(const float2*)(W1 + (size_t)(k + 1) * D_HID + c);
                s0a = fmaf(xv0, w0.x, s0a); s1a = fmaf(xv0, w0.y, s1a);
                s0b = fmaf(xv1, w1.x, s0b); s1b = fmaf(xv1, w1.y, s1b);
            }
            hr[c]     = fmaxf(s0a + s0b + b1[c], 0.f);
            hr[c + 1] = fmaxf(s1a + s1b + b1[c + 1], 0.f);
        }
        __syncthreads();
        {
            float sa = 0.f, sb = 0.f;
            #pragma unroll 4
            for (int k = 0; k < D_HID; k += 2) {
                sa = fmaf(hr[k],     W2[(size_t)k * D_CODE_ + tid],       sa);
                sb = fmaf(hr[k + 1], W2[(size_t)(k + 1) * D_CODE_ + tid], sb);
            }
            er[tid] = sa + sb + b2[tid];
        }
        __syncthreads();
        if (tid < 128) {
            float e2a = 0.f, e2b = 0.f, da = 0.f, db = 0.f;
            const float* cr = cb + (size_t)tid * D_CODE_;
            #pragma unroll 4
            for (int k = 0; k < D_CODE_; k += 2) {
                e2a = fmaf(er[k], er[k], e2a);         e2b = fmaf(er[k + 1], er[k + 1], e2b);
                da  = fmaf(er[k], cr[k], da);          db  = fmaf(er[k + 1], cr[k + 1], db);
            }
            dv[tid] = ((e2a + e2b) - 2.0f * (da + db)) + cbnorm[tid];
            di[tid] = tid;
        }
        __syncthreads();
        for (int st = 64; st >= 1; st >>= 1) {
            if (tid < st) {
                const float a = dv[tid], b = dv[tid + st];
                const int  ib = di[tid + st];
                if (b < a || (b == a && ib < di[tid])) { dv[tid] = b; di[tid] = ib; }
            }
            __syncthreads();
        }
        if (tid == 0) outIdx[row] = (float)di[0];
    }
}

// ---------------------------------------------------------------------------
__global__ void finalize_kernel(const float* __restrict__ accum, float* __restrict__ out)
{
    const float inv = 1.0f / (32768.0f * 256.0f);
    const float loss = (accum[0] + accum[1]) * inv;   // commitment == codebook
    out[32768] = loss;
    out[32769] = loss;
    out[32770] = 1.25f * loss;
}

// ---------------------------------------------------------------------------
extern "C" void kernel_launch(void* const* d_in, const int* in_sizes, int n_in,
                              void* d_out, int out_size, void* d_ws, size_t ws_size,
                              hipStream_t stream)
{
    (void)in_sizes; (void)n_in; (void)out_size; (void)ws_size;

    const float* x  = (const float*)d_in[0];  // [32768,1024]
    const float* W1 = (const float*)d_in[1];  // [1024,512]
    const float* b1 = (const float*)d_in[2];  // [512]
    const float* W2 = (const float*)d_in[3];  // [512,256]
    const float* b2 = (const float*)d_in[4];  // [256]
    const float* cb = (const float*)d_in[5];  // [128,256]
    float* out = (float*)d_out;

    // workspace layout (bytes)
    char* ws = (char*)d_ws;
    _Float16* W1T  = (_Float16*)(ws + 0);                 // 1 MB   [512][1024]
    _Float16* W2T  = (_Float16*)(ws + 1048576);           // 256 KB [256][512]
    _Float16* cb16 = (_Float16*)(ws + 1310720);           // 64 KB  [128][256]
    float*    cbn  = (float*   )(ws + 1376256);           // 512 B
    float*    accum= (float*   )(ws + 1376768);           // 64 B
    int*      cnt  = (int*     )(ws + 1376832);           // 64 B
    int*      list = (int*     )(ws + 1376896);           // 128 KB
    _Float16* h16  = (_Float16*)(ws + (size_t)(2u<<20));              // 32 MB
    _Float16* enc16= (_Float16*)(ws + (size_t)(2u<<20) + 33554432);   // 16 MB

    prep_cb_kernel<<<N_CODES_, 256, 0, stream>>>(cb, cb16, cbn, accum, cnt);
    splitT_kernel<<<dim3(D_INK / 64, D_HID / 64), 256, 0, stream>>>(W1, W1T, D_INK, D_HID);
    splitT_kernel<<<dim3(D_HID / 64, D_CODE_ / 64), 256, 0, stream>>>(W2, W2T, D_HID, D_CODE_);

    gemm1_kernel<<<(M_ROWS / 128) * (D_HID / 128), 256, 0, stream>>>(x, W1T, b1, h16);
    gemm2_kernel<<<(M_ROWS / 128) * (D_CODE_ / 128), 256, 0, stream>>>(h16, W2T, b2, enc16, accum);
    dist_kernel<<<M_ROWS / 128, 256, 0, stream>>>(enc16, cb16, cbn, out, accum, cnt, list);
    fixup_kernel<<<512, 256, 0, stream>>>(x, W1, b1, W2, b2, cb, cbn, cnt, list, out);
    finalize_kernel<<<1, 1, 0, stream>>>(accum, out);
}

// Round 8
// 288.522 us; speedup vs baseline: 1.3594x; 1.0890x over previous
//
#include <hip/hip_runtime.h>
#include <cstddef>
#include <cstdint>

// Problem constants
static constexpr int M_ROWS  = 32768;   // B*T
static constexpr int D_INK   = 1024;
static constexpr int D_HID   = 512;
static constexpr int D_CODE_ = 256;
static constexpr int N_CODES_= 128;

// fp16 single-product pairwise-d2 jitter sigma ~= 0.019  ->  TAU = 10 sigma
static constexpr float TAU_GAP = 0.20f;

using f16x8 = __attribute__((ext_vector_type(8))) _Float16;
using f32x4 = __attribute__((ext_vector_type(4))) float;

// ---------------------------------------------------------------------------
// Packed panel format: one panel = one (128-row tile) x (32-k step):
//   panel[(kq*128 + rc)*8 + j] = src[tile*128 + rc][ks*32 + kq*8 + j]
// 4096 x fp16 = 8 KB contiguous; frag-linear == the LDS layout the MFMA
// fragment reads want, so global->LDS DMA is fully coalesced AND linear.
// ---------------------------------------------------------------------------

__device__ __forceinline__ void dma16(const void* g, void* l) {
    __builtin_amdgcn_global_load_lds(
        (const __attribute__((address_space(1))) void*)g,
        (__attribute__((address_space(3))) void*)l, 16, 0, 0);
}

// stage one 8 KB panel into LDS: 8 dma16 instrs, 2 per wave, lane-contiguous
__device__ __forceinline__ void stage_panel(const _Float16* __restrict__ p,
                                            _Float16* dst, int w, int lane)
{
    #pragma unroll
    for (int ii = 0; ii < 2; ++ii) {
        const int I = 2 * w + ii;           // 0..7 (wave-uniform)
        dma16(p + (size_t)I * 512 + lane * 8, dst + (size_t)I * 512);
    }
}

// one BK=32 compute step: 4x4 fragment tile per wave, single fp16 product
__device__ __forceinline__ void mfma_tile(const _Float16* sA, const _Float16* sB,
                                          int wm, int wn, int kq, int lm,
                                          f32x4 (&acc)[4][4])
{
    f16x8 a[4];
    #pragma unroll
    for (int fm = 0; fm < 4; ++fm)
        a[fm] = *(const f16x8*)(sA + (kq * 128 + wm * 64 + fm * 16 + lm) * 8);
    #pragma unroll
    for (int fn = 0; fn < 4; ++fn) {
        const f16x8 b = *(const f16x8*)(sB + (kq * 128 + wn * 64 + fn * 16 + lm) * 8);
        #pragma unroll
        for (int fm = 0; fm < 4; ++fm)
            acc[fm][fn] = __builtin_amdgcn_mfma_f32_16x16x32_f16(a[fm], b, acc[fm][fn], 0, 0, 0);
    }
}

// bijective XCD swizzle (nwg % 8 == 0): consecutive logical ids -> same XCD L2
__device__ __forceinline__ int xcd_swz(int bid, int nwg) {
    const int q = nwg >> 3;
    return (bid & 7) * q + (bid >> 3);
}

// ---------------------------------------------------------------------------
// prep: codebook -> packed fp16 panels (B-side, rows are codes, NT=8),
// exact per-code norms, zero accumulators.
// ---------------------------------------------------------------------------
__global__ __launch_bounds__(256)
void prep_cb_kernel(const float* __restrict__ cb, _Float16* __restrict__ cbP,
                    float* __restrict__ cbnorm, float* __restrict__ accum,
                    int* __restrict__ cnt)
{
    const int j = blockIdx.x;      // code 0..127
    const int t = threadIdx.x;     // dim 0..255
    const float v = cb[j * D_CODE_ + t];
    const int ks = t >> 5, kq = (t >> 3) & 3, jj = t & 7;
    cbP[((size_t)ks * 512 + kq * 128 + j) * 8 + jj] = (_Float16)v;

    __shared__ float sr[256];
    sr[t] = v * v;
    __syncthreads();
    for (int s = 128; s >= 1; s >>= 1) {
        if (t < s) sr[t] += sr[t + s];
        __syncthreads();
    }
    if (t == 0) cbnorm[j] = sr[0];
    if (j == 0 && t < 2) accum[t] = 0.0f;
    if (j == 0 && t == 2) *cnt = 0;
}

// ---------------------------------------------------------------------------
// pack_w: W [K][N] fp32 -> B-side panels (n-tiles of 128, k-steps of 32).
// Reads are coalesced per (kq,j) row-slice; output contiguous.
// grid = (K/32, N/128)
// ---------------------------------------------------------------------------
__global__ __launch_bounds__(256)
void pack_w_kernel(const float* __restrict__ W, _Float16* __restrict__ WP,
                   int Kd, int Nd)
{
    const int ks = blockIdx.x, nt = blockIdx.y;
    const int t = threadIdx.x;
    _Float16* dst = WP + ((size_t)nt * (Kd >> 5) + ks) * 4096;
    #pragma unroll
    for (int half = 0; half < 2; ++half) {
        const int f = half * 256 + t;
        const int nc = f & 127, kq = f >> 7;
        f16x8 v;
        #pragma unroll
        for (int j = 0; j < 8; ++j)
            v[j] = (_Float16)W[(size_t)(ks * 32 + kq * 8 + j) * Nd + nt * 128 + nc];
        *(f16x8*)(dst + (size_t)f * 8) = v;
    }
}

// ---------------------------------------------------------------------------
// pack_x: x fp32 [M][1024] -> A-side fp16 panels.  Coalesced global reads
// (consecutive lanes, consecutive float4), LDS-tiled, contiguous panel writes.
// grid = (M/128, 1024/128) = (256, 8); block covers 128 rows x 128 k.
// ---------------------------------------------------------------------------
__global__ __launch_bounds__(256)
void pack_x_kernel(const float* __restrict__ X, _Float16* __restrict__ XP)
{
    __shared__ _Float16 sh[128][136];   // 272 B rows: 16B-aligned frag reads
    const int t  = threadIdx.x;
    const int mt = blockIdx.x;          // m-tile
    const int kc = blockIdx.y;          // 128-wide k chunk (4 k-steps)

    const float* src = X + (size_t)mt * 128 * D_INK + kc * 128;
    #pragma unroll
    for (int i = 0; i < 16; ++i) {
        const int idx = i * 256 + t;           // 0..4095
        const int row = idx >> 5, c4 = idx & 31;
        const float4 v = *(const float4*)(src + (size_t)row * D_INK + c4 * 4);
        _Float16* d = &sh[row][c4 * 4];
        d[0] = (_Float16)v.x; d[1] = (_Float16)v.y;
        d[2] = (_Float16)v.z; d[3] = (_Float16)v.w;
    }
    __syncthreads();

    _Float16* dst = XP + ((size_t)mt * 32 + kc * 4) * 4096;
    #pragma unroll
    for (int s = 0; s < 4; ++s) {
        #pragma unroll
        for (int half = 0; half < 2; ++half) {
            const int f = half * 256 + t;
            const int rc = f & 127, kq = f >> 7;
            const f16x8 v = *(const f16x8*)(&sh[rc][s * 32 + kq * 8]);
            *(f16x8*)(dst + (size_t)s * 4096 + (size_t)f * 8) = v;
        }
    }
}

// ---------------------------------------------------------------------------
// GEMM1: h = relu(x @ W1 + b1).  All-packed-DMA staging, dbuf LDS (32 KB),
// one __syncthreads per K-step, 4 blocks/CU, XCD-swizzled n-fast grid.
// Output written directly in gemm2's packed-A layout.
// ---------------------------------------------------------------------------
__global__ __launch_bounds__(256, 4)
void gemm1_kernel(const _Float16* __restrict__ AP, const _Float16* __restrict__ BP,
                  const float* __restrict__ bias, _Float16* __restrict__ CP)
{
    __shared__ _Float16 lds[2][2][4096];   // [buf][A,B]  32 KB

    const int tid  = threadIdx.x;
    const int lane = tid & 63;
    const int w    = tid >> 6;
    const int wm = w >> 1, wn = w & 1;
    const int kq = lane >> 4, lm = lane & 15;

    const int swz = xcd_swz(blockIdx.x, (M_ROWS / 128) * (D_HID / 128));
    const int n0 = (swz & 3) * 128;
    const int m0 = (swz >> 2) * 128;

    const _Float16* Apan = AP + ((size_t)(m0 >> 7) * 32) * 4096;
    const _Float16* Bpan = BP + ((size_t)(n0 >> 7) * 32) * 4096;

    f32x4 acc[4][4] = {};

    stage_panel(Apan, &lds[0][0][0], w, lane);
    stage_panel(Bpan, &lds[0][1][0], w, lane);

    constexpr int NSTEP = D_INK / 32;
    for (int t = 0; t < NSTEP; ++t) {
        const int cur = t & 1, nxt = cur ^ 1;
        __syncthreads();               // buf[cur] staged & visible, buf[nxt] free
        if (t + 1 < NSTEP) {
            stage_panel(Apan + (size_t)(t + 1) * 4096, &lds[nxt][0][0], w, lane);
            stage_panel(Bpan + (size_t)(t + 1) * 4096, &lds[nxt][1][0], w, lane);
        }
        mfma_tile(&lds[cur][0][0], &lds[cur][1][0], wm, wn, kq, lm, acc);
    }

    // epilogue: relu; write in gemm2-packed-A layout (NT=16 over D_HID)
    #pragma unroll
    for (int fn = 0; fn < 4; ++fn) {
        const int col = n0 + wn * 64 + fn * 16 + lm;
        const float bv = bias[col];
        #pragma unroll
        for (int fm = 0; fm < 4; ++fm) {
            #pragma unroll
            for (int r = 0; r < 4; ++r) {
                const int row = m0 + wm * 64 + fm * 16 + kq * 4 + r;
                const float v = fmaxf(acc[fm][fn][r] + bv, 0.0f);
                CP[(((size_t)(row >> 7) * 16 + (col >> 5)) * 512
                    + (size_t)((col >> 3) & 3) * 128 + (row & 127)) * 8 + (col & 7)]
                    = (_Float16)v;
            }
        }
    }
}

// ---------------------------------------------------------------------------
// GEMM2: enc = h @ W2 + b2 (+ sum(enc^2) atomic).  Packed in, packed out.
// ---------------------------------------------------------------------------
__global__ __launch_bounds__(256, 4)
void gemm2_kernel(const _Float16* __restrict__ AP, const _Float16* __restrict__ BP,
                  const float* __restrict__ bias, _Float16* __restrict__ CP,
                  float* __restrict__ accum)
{
    __shared__ _Float16 lds[2][2][4096];

    const int tid  = threadIdx.x;
    const int lane = tid & 63;
    const int w    = tid >> 6;
    const int wm = w >> 1, wn = w & 1;
    const int kq = lane >> 4, lm = lane & 15;

    const int swz = xcd_swz(blockIdx.x, (M_ROWS / 128) * (D_CODE_ / 128));
    const int n0 = (swz & 1) * 128;
    const int m0 = (swz >> 1) * 128;

    const _Float16* Apan = AP + ((size_t)(m0 >> 7) * 16) * 4096;
    const _Float16* Bpan = BP + ((size_t)(n0 >> 7) * 16) * 4096;

    f32x4 acc[4][4] = {};

    stage_panel(Apan, &lds[0][0][0], w, lane);
    stage_panel(Bpan, &lds[0][1][0], w, lane);

    constexpr int NSTEP = D_HID / 32;
    for (int t = 0; t < NSTEP; ++t) {
        const int cur = t & 1, nxt = cur ^ 1;
        __syncthreads();
        if (t + 1 < NSTEP) {
            stage_panel(Apan + (size_t)(t + 1) * 4096, &lds[nxt][0][0], w, lane);
            stage_panel(Bpan + (size_t)(t + 1) * 4096, &lds[nxt][1][0], w, lane);
        }
        mfma_tile(&lds[cur][0][0], &lds[cur][1][0], wm, wn, kq, lm, acc);
    }

    float sumsq = 0.0f;
    #pragma unroll
    for (int fn = 0; fn < 4; ++fn) {
        const int col = n0 + wn * 64 + fn * 16 + lm;
        const float bv = bias[col];
        #pragma unroll
        for (int fm = 0; fm < 4; ++fm) {
            #pragma unroll
            for (int r = 0; r < 4; ++r) {
                const int row = m0 + wm * 64 + fm * 16 + kq * 4 + r;
                const float v = acc[fm][fn][r] + bv;
                sumsq = fmaf(v, v, sumsq);
                CP[(((size_t)(row >> 7) * 8 + (col >> 5)) * 512
                    + (size_t)((col >> 3) & 3) * 128 + (row & 127)) * 8 + (col & 7)]
                    = (_Float16)v;
            }
        }
    }
    #pragma unroll
    for (int mk = 1; mk <= 32; mk <<= 1) sumsq += __shfl_xor(sumsq, mk);
    if (lane == 0) atomicAdd(&accum[1], sumsq);
}

// ---------------------------------------------------------------------------
// dist: dots = enc @ cb^T (one n-block = all 128 codes); argmin epilogue
// with second-best gap flagging + min-term loss sum.
// ---------------------------------------------------------------------------
__global__ __launch_bounds__(256, 4)
void dist_kernel(const _Float16* __restrict__ AP, const _Float16* __restrict__ BP,
                 const float* __restrict__ cbn,
                 float* __restrict__ outIdx, float* __restrict__ accum,
                 int* __restrict__ cnt, int* __restrict__ list)
{
    __shared__ _Float16 lds[2][2][4096];

    const int tid  = threadIdx.x;
    const int lane = tid & 63;
    const int w    = tid >> 6;
    const int wm = w >> 1, wn = w & 1;
    const int kq = lane >> 4, lm = lane & 15;
    const int m0 = blockIdx.x * 128;

    float cbn_l[4];
    #pragma unroll
    for (int fn = 0; fn < 4; ++fn) cbn_l[fn] = cbn[wn * 64 + fn * 16 + lm];

    const _Float16* Apan = AP + ((size_t)(m0 >> 7) * 8) * 4096;

    f32x4 acc[4][4] = {};

    stage_panel(Apan, &lds[0][0][0], w, lane);
    stage_panel(BP,   &lds[0][1][0], w, lane);

    constexpr int NSTEP = D_CODE_ / 32;
    for (int t = 0; t < NSTEP; ++t) {
        const int cur = t & 1, nxt = cur ^ 1;
        __syncthreads();
        if (t + 1 < NSTEP) {
            stage_panel(Apan + (size_t)(t + 1) * 4096, &lds[nxt][0][0], w, lane);
            stage_panel(BP   + (size_t)(t + 1) * 4096, &lds[nxt][1][0], w, lane);
        }
        mfma_tile(&lds[cur][0][0], &lds[cur][1][0], wm, wn, kq, lm, acc);
    }

    __syncthreads();   // all LDS reads done before reuse as epilogue scratch
    float* eb1 = (float*)&lds[0][0][0];        // [2][128]
    float* eb2 = eb1 + 256;
    int*   eix = (int*)(eb2 + 256);

    #pragma unroll
    for (int fm = 0; fm < 4; ++fm) {
        #pragma unroll
        for (int r = 0; r < 4; ++r) {
            float b1v = 3.4e38f, b2v = 3.4e38f; int bi = 0;
            #pragma unroll
            for (int fn = 0; fn < 4; ++fn) {
                const float v = fmaf(-2.0f, acc[fm][fn][r], cbn_l[fn]);
                if (v < b1v) { b2v = b1v; b1v = v; bi = wn * 64 + fn * 16 + lm; }
                else if (v < b2v) b2v = v;
            }
            #pragma unroll
            for (int mk = 1; mk <= 8; mk <<= 1) {
                const float o1 = __shfl_xor(b1v, mk);
                const float o2 = __shfl_xor(b2v, mk);
                const int   oi = __shfl_xor(bi,  mk);
                if (o1 < b1v || (o1 == b1v && oi < bi)) { b2v = fminf(b1v, o2); b1v = o1; bi = oi; }
                else b2v = fminf(b2v, o1);
            }
            const int rl = wm * 64 + fm * 16 + kq * 4 + r;
            if (lm == 0) { eb1[wn * 128 + rl] = b1v; eb2[wn * 128 + rl] = b2v; eix[wn * 128 + rl] = bi; }
        }
    }
    __syncthreads();

    if (tid < 128) {
        const int rl = tid;
        const float a1 = eb1[rl], a2 = eb2[rl]; const int ai = eix[rl];
        const float o1 = eb1[128 + rl], o2 = eb2[128 + rl]; const int oi = eix[128 + rl];
        float B1, B2; int BI;
        if (o1 < a1 || (o1 == a1 && oi < ai)) { B1 = o1; BI = oi; B2 = fminf(a1, o2); }
        else                                  { B1 = a1; BI = ai; B2 = fminf(a2, o1); }
        outIdx[m0 + rl] = (float)BI;
        if (B2 - B1 < TAU_GAP) { const int p = atomicAdd(cnt, 1); list[p] = m0 + rl; }
        float s = B1;
        #pragma unroll
        for (int mk = 1; mk <= 32; mk <<= 1) s += __shfl_xor(s, mk);
        if (lane == 0) atomicAdd(&accum[0], s);
    }
}

// ---------------------------------------------------------------------------
// fixup: exact fp32 recompute of flagged (near-tie) rows; overwrite index.
// ---------------------------------------------------------------------------
__global__ __launch_bounds__(256)
void fixup_kernel(const float* __restrict__ x, const float* __restrict__ W1,
                  const float* __restrict__ b1, const float* __restrict__ W2,
                  const float* __restrict__ b2, const float* __restrict__ cb,
                  const float* __restrict__ cbnorm,
                  const int* __restrict__ cnt, const int* __restrict__ list,
                  float* __restrict__ outIdx)
{
    __shared__ float xr[1024];
    __shared__ float hr[512];
    __shared__ float er[256];
    __shared__ float dv[128];
    __shared__ int   di[128];

    const int tid = threadIdx.x;
    const int n = *cnt;
    for (int it = blockIdx.x; it < n; it += gridDim.x) {
        const int row = list[it];
        __syncthreads();
        #pragma unroll
        for (int i = 0; i < 4; ++i)
            xr[tid + i * 256] = x[(size_t)row * D_INK + tid + i * 256];
        __syncthreads();
        {
            const int c = tid * 2;
            float s0a = 0.f, s0b = 0.f, s1a = 0.f, s1b = 0.f;
            #pragma unroll 4
            for (int k = 0; k < D_INK; k += 2) {
                const float xv0 = xr[k], xv1 = xr[k + 1];
                const float2 w0 = *(const float2*)(W1 + (size_t)k * D_HID + c);
                const float2 w1 = *(const float2*)(W1 + (size_t)(k + 1) * D_HID + c);
                s0a = fmaf(xv0, w0.x, s0a); s1a = fmaf(xv0, w0.y, s1a);
                s0b = fmaf(xv1, w1.x, s0b); s1b = fmaf(xv1, w1.y, s1b);
            }
            hr[c]     = fmaxf(s0a + s0b + b1[c], 0.f);
            hr[c + 1] = fmaxf(s1a + s1b + b1[c + 1], 0.f);
        }
        __syncthreads();
        {
            float sa = 0.f, sb = 0.f;
            #pragma unroll 4
            for (int k = 0; k < D_HID; k += 2) {
                sa = fmaf(hr[k],     W2[(size_t)k * D_CODE_ + tid],       sa);
                sb = fmaf(hr[k + 1], W2[(size_t)(k + 1) * D_CODE_ + tid], sb);
            }
            er[tid] = sa + sb + b2[tid];
        }
        __syncthreads();
        if (tid < 128) {
            float e2a = 0.f, e2b = 0.f, da = 0.f, db = 0.f;
            const float* cr = cb + (size_t)tid * D_CODE_;
            #pragma unroll 4
            for (int k = 0; k < D_CODE_; k += 2) {
                e2a = fmaf(er[k], er[k], e2a);         e2b = fmaf(er[k + 1], er[k + 1], e2b);
                da  = fmaf(er[k], cr[k], da);          db  = fmaf(er[k + 1], cr[k + 1], db);
            }
            dv[tid] = ((e2a + e2b) - 2.0f * (da + db)) + cbnorm[tid];
            di[tid] = tid;
        }
        __syncthreads();
        for (int st = 64; st >= 1; st >>= 1) {
            if (tid < st) {
                const float a = dv[tid], b = dv[tid + st];
                const int  ib = di[tid + st];
                if (b < a || (b == a && ib < di[tid])) { dv[tid] = b; di[tid] = ib; }
            }
            __syncthreads();
        }
        if (tid == 0) outIdx[row] = (float)di[0];
    }
}

// ---------------------------------------------------------------------------
__global__ void finalize_kernel(const float* __restrict__ accum, float* __restrict__ out)
{
    const float inv = 1.0f / (32768.0f * 256.0f);
    const float loss = (accum[0] + accum[1]) * inv;   // commitment == codebook
    out[32768] = loss;
    out[32769] = loss;
    out[32770] = 1.25f * loss;
}

// ---------------------------------------------------------------------------
extern "C" void kernel_launch(void* const* d_in, const int* in_sizes, int n_in,
                              void* d_out, int out_size, void* d_ws, size_t ws_size,
                              hipStream_t stream)
{
    (void)in_sizes; (void)n_in; (void)out_size; (void)ws_size;

    const float* x  = (const float*)d_in[0];  // [32768,1024]
    const float* W1 = (const float*)d_in[1];  // [1024,512]
    const float* b1 = (const float*)d_in[2];  // [512]
    const float* W2 = (const float*)d_in[3];  // [512,256]
    const float* b2 = (const float*)d_in[4];  // [256]
    const float* cb = (const float*)d_in[5];  // [128,256]
    float* out = (float*)d_out;

    // workspace layout (bytes); encP overlaps xP (xP dead after gemm1)
    char* ws = (char*)d_ws;
    _Float16* W1P  = (_Float16*)(ws + 0);                 // 1 MB   (4 nt x 32 ks)
    _Float16* W2P  = (_Float16*)(ws + 1048576);           // 256 KB (2 nt x 16 ks)
    _Float16* cbP  = (_Float16*)(ws + 1310720);           // 64 KB  (1 nt x 8 ks)
    float*    cbn  = (float*   )(ws + 1376256);           // 512 B
    float*    accum= (float*   )(ws + 1376768);           // 64 B
    int*      cnt  = (int*     )(ws + 1376832);           // 64 B
    int*      list = (int*     )(ws + 1376896);           // 128 KB
    _Float16* xP   = (_Float16*)(ws + (size_t)(2u<<20));              // 64 MB
    _Float16* encP = (_Float16*)(ws + (size_t)(2u<<20));              // 16 MB (reuse)
    _Float16* hP   = (_Float16*)(ws + (size_t)(2u<<20) + 67108864);   // 32 MB

    prep_cb_kernel<<<N_CODES_, 256, 0, stream>>>(cb, cbP, cbn, accum, cnt);
    pack_w_kernel<<<dim3(D_INK / 32, D_HID / 128), 256, 0, stream>>>(W1, W1P, D_INK, D_HID);
    pack_w_kernel<<<dim3(D_HID / 32, D_CODE_ / 128), 256, 0, stream>>>(W2, W2P, D_HID, D_CODE_);
    pack_x_kernel<<<dim3(M_ROWS / 128, D_INK / 128), 256, 0, stream>>>(x, xP);

    gemm1_kernel<<<(M_ROWS / 128) * (D_HID / 128), 256, 0, stream>>>(xP, W1P, b1, hP);
    gemm2_kernel<<<(M_ROWS / 128) * (D_CODE_ / 128), 256, 0, stream>>>(hP, W2P, b2, encP, accum);
    dist_kernel<<<M_ROWS / 128, 256, 0, stream>>>(encP, cbP, cbn, out, accum, cnt, list);
    fixup_kernel<<<512, 256, 0, stream>>>(x, W1, b1, W2, b2, cb, cbn, cnt, list, out);
    finalize_kernel<<<1, 1, 0, stream>>>(accum, out);
}

// Round 9
// 268.622 us; speedup vs baseline: 1.4601x; 1.0741x over previous
//
#include <hip/hip_runtime.h>
#include <cstddef>
#include <cstdint>

// Problem constants
static constexpr int M_ROWS  = 32768;   // B*T
static constexpr int D_INK   = 1024;
static constexpr int D_HID   = 512;
static constexpr int D_CODE_ = 256;
static constexpr int N_CODES_= 128;

// fp16 single-product pairwise-d2 jitter sigma ~= 0.019  ->  TAU = 10 sigma
static constexpr float TAU_GAP = 0.20f;

using f16x8 = __attribute__((ext_vector_type(8))) _Float16;
using f32x4 = __attribute__((ext_vector_type(4))) float;

// ---------------------------------------------------------------------------
// Packed panel format: one panel = one (128-row tile) x (32-k step):
//   panel[(kq*128 + rc)*8 + j] = src[tile*128 + rc][ks*32 + kq*8 + j]
// 4096 x fp16 = 8 KB contiguous; frag-linear == the LDS layout the MFMA
// fragment reads want, so global->LDS DMA is fully coalesced AND linear.
// ---------------------------------------------------------------------------

__device__ __forceinline__ void dma16(const void* g, void* l) {
    __builtin_amdgcn_global_load_lds(
        (const __attribute__((address_space(1))) void*)g,
        (__attribute__((address_space(3))) void*)l, 16, 0, 0);
}

// stage one 8 KB panel into LDS: 8 dma16 instrs, 2 per wave, lane-contiguous
__device__ __forceinline__ void stage_panel(const _Float16* __restrict__ p,
                                            _Float16* dst, int w, int lane)
{
    #pragma unroll
    for (int ii = 0; ii < 2; ++ii) {
        const int I = 2 * w + ii;           // 0..7 (wave-uniform)
        dma16(p + (size_t)I * 512 + lane * 8, dst + (size_t)I * 512);
    }
}

// one BK=32 compute step: 4x4 fragment tile per wave, single fp16 product
__device__ __forceinline__ void mfma_tile(const _Float16* sA, const _Float16* sB,
                                          int wm, int wn, int kq, int lm,
                                          f32x4 (&acc)[4][4])
{
    f16x8 a[4];
    #pragma unroll
    for (int fm = 0; fm < 4; ++fm)
        a[fm] = *(const f16x8*)(sA + (kq * 128 + wm * 64 + fm * 16 + lm) * 8);
    #pragma unroll
    for (int fn = 0; fn < 4; ++fn) {
        const f16x8 b = *(const f16x8*)(sB + (kq * 128 + wn * 64 + fn * 16 + lm) * 8);
        #pragma unroll
        for (int fm = 0; fm < 4; ++fm)
            acc[fm][fn] = __builtin_amdgcn_mfma_f32_16x16x32_f16(a[fm], b, acc[fm][fn], 0, 0, 0);
    }
}

// bijective XCD swizzle (nwg % 8 == 0): consecutive logical ids -> same XCD L2
__device__ __forceinline__ int xcd_swz(int bid, int nwg) {
    const int q = nwg >> 3;
    return (bid & 7) * q + (bid >> 3);
}

// ---------------------------------------------------------------------------
// prep: codebook -> packed fp16 panels (B-side) + fp32 transposed copy
// (for coalesced fixup distance reads), exact per-code norms, zero accums.
// ---------------------------------------------------------------------------
__global__ __launch_bounds__(256)
void prep_cb_kernel(const float* __restrict__ cb, _Float16* __restrict__ cbP,
                    float* __restrict__ cbT,
                    float* __restrict__ cbnorm, float* __restrict__ accum,
                    int* __restrict__ cnt)
{
    const int j = blockIdx.x;      // code 0..127
    const int t = threadIdx.x;     // dim 0..255
    const float v = cb[j * D_CODE_ + t];
    const int ks = t >> 5, kq = (t >> 3) & 3, jj = t & 7;
    cbP[((size_t)ks * 512 + kq * 128 + j) * 8 + jj] = (_Float16)v;
    cbT[(size_t)t * N_CODES_ + j] = v;

    __shared__ float sr[256];
    sr[t] = v * v;
    __syncthreads();
    for (int s = 128; s >= 1; s >>= 1) {
        if (t < s) sr[t] += sr[t + s];
        __syncthreads();
    }
    if (t == 0) cbnorm[j] = sr[0];
    if (j == 0 && t < 2) accum[t] = 0.0f;
    if (j == 0 && t == 2) *cnt = 0;
}

// ---------------------------------------------------------------------------
// pack_w: W [K][N] fp32 -> B-side panels (n-tiles of 128, k-steps of 32).
// ---------------------------------------------------------------------------
__global__ __launch_bounds__(256)
void pack_w_kernel(const float* __restrict__ W, _Float16* __restrict__ WP,
                   int Kd, int Nd)
{
    const int ks = blockIdx.x, nt = blockIdx.y;
    const int t = threadIdx.x;
    _Float16* dst = WP + ((size_t)nt * (Kd >> 5) + ks) * 4096;
    #pragma unroll
    for (int half = 0; half < 2; ++half) {
        const int f = half * 256 + t;
        const int nc = f & 127, kq = f >> 7;
        f16x8 v;
        #pragma unroll
        for (int j = 0; j < 8; ++j)
            v[j] = (_Float16)W[(size_t)(ks * 32 + kq * 8 + j) * Nd + nt * 128 + nc];
        *(f16x8*)(dst + (size_t)f * 8) = v;
    }
}

// ---------------------------------------------------------------------------
// pack_x: x fp32 [M][1024] -> A-side fp16 panels.  Coalesced reads,
// LDS-tiled, contiguous panel writes.  grid = (M/128, 8).
// ---------------------------------------------------------------------------
__global__ __launch_bounds__(256)
void pack_x_kernel(const float* __restrict__ X, _Float16* __restrict__ XP)
{
    __shared__ _Float16 sh[128][136];   // 272 B rows: 16B-aligned frag reads
    const int t  = threadIdx.x;
    const int mt = blockIdx.x;          // m-tile
    const int kc = blockIdx.y;          // 128-wide k chunk (4 k-steps)

    const float* src = X + (size_t)mt * 128 * D_INK + kc * 128;
    #pragma unroll
    for (int i = 0; i < 16; ++i) {
        const int idx = i * 256 + t;           // 0..4095
        const int row = idx >> 5, c4 = idx & 31;
        const float4 v = *(const float4*)(src + (size_t)row * D_INK + c4 * 4);
        _Float16* d = &sh[row][c4 * 4];
        d[0] = (_Float16)v.x; d[1] = (_Float16)v.y;
        d[2] = (_Float16)v.z; d[3] = (_Float16)v.w;
    }
    __syncthreads();

    _Float16* dst = XP + ((size_t)mt * 32 + kc * 4) * 4096;
    #pragma unroll
    for (int s = 0; s < 4; ++s) {
        #pragma unroll
        for (int half = 0; half < 2; ++half) {
            const int f = half * 256 + t;
            const int rc = f & 127, kq = f >> 7;
            const f16x8 v = *(const f16x8*)(&sh[rc][s * 32 + kq * 8]);
            *(f16x8*)(dst + (size_t)s * 4096 + (size_t)f * 8) = v;
        }
    }
}

// ---------------------------------------------------------------------------
// GEMM1: h = relu(x @ W1 + b1).  All-packed-DMA staging, dbuf LDS (32 KB),
// one __syncthreads per K-step, 4 blocks/CU, XCD-swizzled n-fast grid.
// Output written directly in gemm2's packed-A layout.
// ---------------------------------------------------------------------------
__global__ __launch_bounds__(256, 4)
void gemm1_kernel(const _Float16* __restrict__ AP, const _Float16* __restrict__ BP,
                  const float* __restrict__ bias, _Float16* __restrict__ CP)
{
    __shared__ _Float16 lds[2][2][4096];   // [buf][A,B]  32 KB

    const int tid  = threadIdx.x;
    const int lane = tid & 63;
    const int w    = tid >> 6;
    const int wm = w >> 1, wn = w & 1;
    const int kq = lane >> 4, lm = lane & 15;

    const int swz = xcd_swz(blockIdx.x, (M_ROWS / 128) * (D_HID / 128));
    const int n0 = (swz & 3) * 128;
    const int m0 = (swz >> 2) * 128;

    const _Float16* Apan = AP + ((size_t)(m0 >> 7) * 32) * 4096;
    const _Float16* Bpan = BP + ((size_t)(n0 >> 7) * 32) * 4096;

    f32x4 acc[4][4] = {};

    stage_panel(Apan, &lds[0][0][0], w, lane);
    stage_panel(Bpan, &lds[0][1][0], w, lane);

    constexpr int NSTEP = D_INK / 32;
    for (int t = 0; t < NSTEP; ++t) {
        const int cur = t & 1, nxt = cur ^ 1;
        __syncthreads();               // buf[cur] staged & visible, buf[nxt] free
        if (t + 1 < NSTEP) {
            stage_panel(Apan + (size_t)(t + 1) * 4096, &lds[nxt][0][0], w, lane);
            stage_panel(Bpan + (size_t)(t + 1) * 4096, &lds[nxt][1][0], w, lane);
        }
        mfma_tile(&lds[cur][0][0], &lds[cur][1][0], wm, wn, kq, lm, acc);
    }

    // epilogue: relu; write in gemm2-packed-A layout (NT=16 over D_HID)
    #pragma unroll
    for (int fn = 0; fn < 4; ++fn) {
        const int col = n0 + wn * 64 + fn * 16 + lm;
        const float bv = bias[col];
        #pragma unroll
        for (int fm = 0; fm < 4; ++fm) {
            #pragma unroll
            for (int r = 0; r < 4; ++r) {
                const int row = m0 + wm * 64 + fm * 16 + kq * 4 + r;
                const float v = fmaxf(acc[fm][fn][r] + bv, 0.0f);
                CP[(((size_t)(row >> 7) * 16 + (col >> 5)) * 512
                    + (size_t)((col >> 3) & 3) * 128 + (row & 127)) * 8 + (col & 7)]
                    = (_Float16)v;
            }
        }
    }
}

// ---------------------------------------------------------------------------
// GEMM2: enc = h @ W2 + b2 (+ sum(enc^2) atomic).  Packed in, packed out.
// ---------------------------------------------------------------------------
__global__ __launch_bounds__(256, 4)
void gemm2_kernel(const _Float16* __restrict__ AP, const _Float16* __restrict__ BP,
                  const float* __restrict__ bias, _Float16* __restrict__ CP,
                  float* __restrict__ accum)
{
    __shared__ _Float16 lds[2][2][4096];

    const int tid  = threadIdx.x;
    const int lane = tid & 63;
    const int w    = tid >> 6;
    const int wm = w >> 1, wn = w & 1;
    const int kq = lane >> 4, lm = lane & 15;

    const int swz = xcd_swz(blockIdx.x, (M_ROWS / 128) * (D_CODE_ / 128));
    const int n0 = (swz & 1) * 128;
    const int m0 = (swz >> 1) * 128;

    const _Float16* Apan = AP + ((size_t)(m0 >> 7) * 16) * 4096;
    const _Float16* Bpan = BP + ((size_t)(n0 >> 7) * 16) * 4096;

    f32x4 acc[4][4] = {};

    stage_panel(Apan, &lds[0][0][0], w, lane);
    stage_panel(Bpan, &lds[0][1][0], w, lane);

    constexpr int NSTEP = D_HID / 32;
    for (int t = 0; t < NSTEP; ++t) {
        const int cur = t & 1, nxt = cur ^ 1;
        __syncthreads();
        if (t + 1 < NSTEP) {
            stage_panel(Apan + (size_t)(t + 1) * 4096, &lds[nxt][0][0], w, lane);
            stage_panel(Bpan + (size_t)(t + 1) * 4096, &lds[nxt][1][0], w, lane);
        }
        mfma_tile(&lds[cur][0][0], &lds[cur][1][0], wm, wn, kq, lm, acc);
    }

    float sumsq = 0.0f;
    #pragma unroll
    for (int fn = 0; fn < 4; ++fn) {
        const int col = n0 + wn * 64 + fn * 16 + lm;
        const float bv = bias[col];
        #pragma unroll
        for (int fm = 0; fm < 4; ++fm) {
            #pragma unroll
            for (int r = 0; r < 4; ++r) {
                const int row = m0 + wm * 64 + fm * 16 + kq * 4 + r;
                const float v = acc[fm][fn][r] + bv;
                sumsq = fmaf(v, v, sumsq);
                CP[(((size_t)(row >> 7) * 8 + (col >> 5)) * 512
                    + (size_t)((col >> 3) & 3) * 128 + (row & 127)) * 8 + (col & 7)]
                    = (_Float16)v;
            }
        }
    }
    #pragma unroll
    for (int mk = 1; mk <= 32; mk <<= 1) sumsq += __shfl_xor(sumsq, mk);
    if (lane == 0) atomicAdd(&accum[1], sumsq);
}

// ---------------------------------------------------------------------------
// dist: dots = enc @ cb^T (one n-block = all 128 codes); argmin epilogue
// with second-best gap flagging + min-term loss sum.
// ---------------------------------------------------------------------------
__global__ __launch_bounds__(256, 4)
void dist_kernel(const _Float16* __restrict__ AP, const _Float16* __restrict__ BP,
                 const float* __restrict__ cbn,
                 float* __restrict__ outIdx, float* __restrict__ accum,
                 int* __restrict__ cnt, int* __restrict__ list)
{
    __shared__ _Float16 lds[2][2][4096];

    const int tid  = threadIdx.x;
    const int lane = tid & 63;
    const int w    = tid >> 6;
    const int wm = w >> 1, wn = w & 1;
    const int kq = lane >> 4, lm = lane & 15;
    const int m0 = blockIdx.x * 128;

    float cbn_l[4];
    #pragma unroll
    for (int fn = 0; fn < 4; ++fn) cbn_l[fn] = cbn[wn * 64 + fn * 16 + lm];

    const _Float16* Apan = AP + ((size_t)(m0 >> 7) * 8) * 4096;

    f32x4 acc[4][4] = {};

    stage_panel(Apan, &lds[0][0][0], w, lane);
    stage_panel(BP,   &lds[0][1][0], w, lane);

    constexpr int NSTEP = D_CODE_ / 32;
    for (int t = 0; t < NSTEP; ++t) {
        const int cur = t & 1, nxt = cur ^ 1;
        __syncthreads();
        if (t + 1 < NSTEP) {
            stage_panel(Apan + (size_t)(t + 1) * 4096, &lds[nxt][0][0], w, lane);
            stage_panel(BP   + (size_t)(t + 1) * 4096, &lds[nxt][1][0], w, lane);
        }
        mfma_tile(&lds[cur][0][0], &lds[cur][1][0], wm, wn, kq, lm, acc);
    }

    __syncthreads();   // all LDS reads done before reuse as epilogue scratch
    float* eb1 = (float*)&lds[0][0][0];        // [2][128]
    float* eb2 = eb1 + 256;
    int*   eix = (int*)(eb2 + 256);

    #pragma unroll
    for (int fm = 0; fm < 4; ++fm) {
        #pragma unroll
        for (int r = 0; r < 4; ++r) {
            float b1v = 3.4e38f, b2v = 3.4e38f; int bi = 0;
            #pragma unroll
            for (int fn = 0; fn < 4; ++fn) {
                const float v = fmaf(-2.0f, acc[fm][fn][r], cbn_l[fn]);
                if (v < b1v) { b2v = b1v; b1v = v; bi = wn * 64 + fn * 16 + lm; }
                else if (v < b2v) b2v = v;
            }
            #pragma unroll
            for (int mk = 1; mk <= 8; mk <<= 1) {
                const float o1 = __shfl_xor(b1v, mk);
                const float o2 = __shfl_xor(b2v, mk);
                const int   oi = __shfl_xor(bi,  mk);
                if (o1 < b1v || (o1 == b1v && oi < bi)) { b2v = fminf(b1v, o2); b1v = o1; bi = oi; }
                else b2v = fminf(b2v, o1);
            }
            const int rl = wm * 64 + fm * 16 + kq * 4 + r;
            if (lm == 0) { eb1[wn * 128 + rl] = b1v; eb2[wn * 128 + rl] = b2v; eix[wn * 128 + rl] = bi; }
        }
    }
    __syncthreads();

    if (tid < 128) {
        const int rl = tid;
        const float a1 = eb1[rl], a2 = eb2[rl]; const int ai = eix[rl];
        const float o1 = eb1[128 + rl], o2 = eb2[128 + rl]; const int oi = eix[128 + rl];
        float B1, B2; int BI;
        if (o1 < a1 || (o1 == a1 && oi < ai)) { B1 = o1; BI = oi; B2 = fminf(a1, o2); }
        else                                  { B1 = a1; BI = ai; B2 = fminf(a2, o1); }
        outIdx[m0 + rl] = (float)BI;
        if (B2 - B1 < TAU_GAP) { const int p = atomicAdd(cnt, 1); list[p] = m0 + rl; }
        float s = B1;
        #pragma unroll
        for (int mk = 1; mk <= 32; mk <<= 1) s += __shfl_xor(s, mk);
        if (lane == 0) atomicAdd(&accum[0], s);
    }
}

// ---------------------------------------------------------------------------
// fixup: exact fp32 recompute of flagged rows, BATCHED 8 rows per block pass
// (W1/W2 read once per 8 rows; 16 independent accumulator chains per thread).
// ---------------------------------------------------------------------------
__global__ __launch_bounds__(256)
void fixup_kernel(const float* __restrict__ x, const float* __restrict__ W1,
                  const float* __restrict__ b1, const float* __restrict__ W2,
                  const float* __restrict__ b2, const float* __restrict__ cbT,
                  const float* __restrict__ cbnorm,
                  const int* __restrict__ cnt, const int* __restrict__ list,
                  float* __restrict__ outIdx)
{
    __shared__ float xr[8][1024];   // 32 KB
    __shared__ float hr[8][512];    // 16 KB
    __shared__ float er[8][256];    //  8 KB
    __shared__ float dv[8][128];    //  4 KB
    __shared__ int   di[8][128];    //  4 KB

    const int tid = threadIdx.x;
    const int n = *cnt;
    const int ngroups = (n + 7) >> 3;

    for (int g = blockIdx.x; g < ngroups; g += gridDim.x) {
        const int base = g * 8;
        const int nr = n - base < 8 ? n - base : 8;
        __syncthreads();   // LDS reuse guard across group iterations
        #pragma unroll
        for (int r = 0; r < 8; ++r) {
            if (r < nr) {
                const int row = list[base + r];
                *(float4*)&xr[r][tid * 4] =
                    *(const float4*)(x + (size_t)row * D_INK + tid * 4);
            }
        }
        __syncthreads();

        // h = relu(x @ W1 + b1): thread owns cols (2c, 2c+1), all 8 rows
        {
            const int c = tid * 2;
            float a0[8], a1[8];
            #pragma unroll
            for (int r = 0; r < 8; ++r) { a0[r] = 0.f; a1[r] = 0.f; }
            for (int k = 0; k < D_INK; ++k) {
                const float2 wv = *(const float2*)(W1 + (size_t)k * D_HID + c);
                #pragma unroll
                for (int r = 0; r < 8; ++r) {
                    const float xv = xr[r][k];      // LDS broadcast
                    a0[r] = fmaf(xv, wv.x, a0[r]);
                    a1[r] = fmaf(xv, wv.y, a1[r]);
                }
            }
            #pragma unroll
            for (int r = 0; r < 8; ++r) {
                hr[r][c]     = fmaxf(a0[r] + b1[c], 0.f);
                hr[r][c + 1] = fmaxf(a1[r] + b1[c + 1], 0.f);
            }
        }
        __syncthreads();

        // enc = h @ W2 + b2: thread owns col tid, all 8 rows
        {
            float a[8];
            #pragma unroll
            for (int r = 0; r < 8; ++r) a[r] = 0.f;
            for (int k = 0; k < D_HID; ++k) {
                const float wv = W2[(size_t)k * D_CODE_ + tid];
                #pragma unroll
                for (int r = 0; r < 8; ++r)
                    a[r] = fmaf(hr[r][k], wv, a[r]);
            }
            #pragma unroll
            for (int r = 0; r < 8; ++r)
                er[r][tid] = a[r] + b2[tid];
        }
        __syncthreads();

        // distances (reference expanded form): thread (j = tid&127,
        // half = tid>>7) handles rows half*4 .. half*4+3; cbT coalesced.
        {
            const int j = tid & 127, half = tid >> 7;
            float e2[4], dt[4];
            #pragma unroll
            for (int q = 0; q < 4; ++q) { e2[q] = 0.f; dt[q] = 0.f; }
            for (int k = 0; k < D_CODE_; ++k) {
                const float cv = cbT[(size_t)k * N_CODES_ + j];
                #pragma unroll
                for (int q = 0; q < 4; ++q) {
                    const float ev = er[half * 4 + q][k];
                    e2[q] = fmaf(ev, ev, e2[q]);
                    dt[q] = fmaf(ev, cv, dt[q]);
                }
            }
            #pragma unroll
            for (int q = 0; q < 4; ++q) {
                dv[half * 4 + q][j] = (e2[q] - 2.0f * dt[q]) + cbnorm[j];
                di[half * 4 + q][j] = j;
            }
        }
        __syncthreads();

        // argmin reduce: 2 passes x 4 rows, 64 threads per row
        #pragma unroll
        for (int pass = 0; pass < 2; ++pass) {
            const int r = pass * 4 + (tid >> 6);
            const int i = tid & 63;
            {   // st = 64: partner index i+64 > i, so ties keep lower index
                const float a = dv[r][i], b = dv[r][i + 64];
                const int  ib = di[r][i + 64];
                if (b < a) { dv[r][i] = b; di[r][i] = ib; }
            }
            __syncthreads();
            for (int st = 32; st >= 1; st >>= 1) {
                if (i < st) {
                    const float a = dv[r][i], b = dv[r][i + st];
                    const int  ib = di[r][i + st];
                    if (b < a || (b == a && ib < di[r][i])) { dv[r][i] = b; di[r][i] = ib; }
                }
                __syncthreads();
            }
        }
        if (tid < nr) outIdx[list[base + tid]] = (float)di[tid][0];
    }
}

// ---------------------------------------------------------------------------
__global__ void finalize_kernel(const float* __restrict__ accum, float* __restrict__ out)
{
    const float inv = 1.0f / (32768.0f * 256.0f);
    const float loss = (accum[0] + accum[1]) * inv;   // commitment == codebook
    out[32768] = loss;
    out[32769] = loss;
    out[32770] = 1.25f * loss;
}

// ---------------------------------------------------------------------------
extern "C" void kernel_launch(void* const* d_in, const int* in_sizes, int n_in,
                              void* d_out, int out_size, void* d_ws, size_t ws_size,
                              hipStream_t stream)
{
    (void)in_sizes; (void)n_in; (void)out_size; (void)ws_size;

    const float* x  = (const float*)d_in[0];  // [32768,1024]
    const float* W1 = (const float*)d_in[1];  // [1024,512]
    const float* b1 = (const float*)d_in[2];  // [512]
    const float* W2 = (const float*)d_in[3];  // [512,256]
    const float* b2 = (const float*)d_in[4];  // [256]
    const float* cb = (const float*)d_in[5];  // [128,256]
    float* out = (float*)d_out;

    // workspace layout (bytes); encP overlaps xP (xP dead after gemm1)
    char* ws = (char*)d_ws;
    _Float16* W1P  = (_Float16*)(ws + 0);                 // 1 MB   (4 nt x 32 ks)
    _Float16* W2P  = (_Float16*)(ws + 1048576);           // 256 KB (2 nt x 16 ks)
    _Float16* cbP  = (_Float16*)(ws + 1310720);           // 64 KB  (1 nt x 8 ks)
    float*    cbn  = (float*   )(ws + 1376256);           // 512 B
    float*    accum= (float*   )(ws + 1376768);           // 64 B
    int*      cnt  = (int*     )(ws + 1376832);           // 64 B
    int*      list = (int*     )(ws + 1376896);           // 128 KB
    float*    cbT  = (float*   )(ws + 1507968);           // 128 KB fp32 [256][128]
    _Float16* xP   = (_Float16*)(ws + (size_t)(2u<<20));              // 64 MB
    _Float16* encP = (_Float16*)(ws + (size_t)(2u<<20));              // 16 MB (reuse)
    _Float16* hP   = (_Float16*)(ws + (size_t)(2u<<20) + 67108864);   // 32 MB

    prep_cb_kernel<<<N_CODES_, 256, 0, stream>>>(cb, cbP, cbT, cbn, accum, cnt);
    pack_w_kernel<<<dim3(D_INK / 32, D_HID / 128), 256, 0, stream>>>(W1, W1P, D_INK, D_HID);
    pack_w_kernel<<<dim3(D_HID / 32, D_CODE_ / 128), 256, 0, stream>>>(W2, W2P, D_HID, D_CODE_);
    pack_x_kernel<<<dim3(M_ROWS / 128, D_INK / 128), 256, 0, stream>>>(x, xP);

    gemm1_kernel<<<(M_ROWS / 128) * (D_HID / 128), 256, 0, stream>>>(xP, W1P, b1, hP);
    gemm2_kernel<<<(M_ROWS / 128) * (D_CODE_ / 128), 256, 0, stream>>>(hP, W2P, b2, encP, accum);
    dist_kernel<<<M_ROWS / 128, 256, 0, stream>>>(encP, cbP, cbn, out, accum, cnt, list);
    fixup_kernel<<<256, 256, 0, stream>>>(x, W1, b1, W2, b2, cbT, cbn, cnt, list, out);
    finalize_kernel<<<1, 1, 0, stream>>>(accum, out);
}

// Round 10
// 253.205 us; speedup vs baseline: 1.5490x; 1.0609x over previous
//
#include <hip/hip_runtime.h>
#include <cstddef>
#include <cstdint>

// Problem constants
static constexpr int M_ROWS  = 32768;   // B*T
static constexpr int D_INK   = 1024;
static constexpr int D_HID   = 512;
static constexpr int D_CODE_ = 256;
static constexpr int N_CODES_= 128;

// fp16 single-product pairwise-d2 gap jitter sigma ~= 0.023 -> TAU = 6.5 sigma
static constexpr float TAU_GAP = 0.15f;

using f16x8 = __attribute__((ext_vector_type(8))) _Float16;
using f32x4 = __attribute__((ext_vector_type(4))) float;

__device__ __forceinline__ float rdlane(float v, int kk) {
    return __uint_as_float(__builtin_amdgcn_readlane(__float_as_uint(v), kk));
}

// ---------------------------------------------------------------------------
// Packed panel format: one panel = one (128-row tile) x (32-k step):
//   panel[(kq*128 + rc)*8 + j] = src[tile*128 + rc][ks*32 + kq*8 + j]
// 4096 x fp16 = 8 KB contiguous; frag-linear == the LDS layout the MFMA
// fragment reads want, so global->LDS DMA is fully coalesced AND linear.
// ---------------------------------------------------------------------------

__device__ __forceinline__ void dma16(const void* g, void* l) {
    __builtin_amdgcn_global_load_lds(
        (const __attribute__((address_space(1))) void*)g,
        (__attribute__((address_space(3))) void*)l, 16, 0, 0);
}

// stage one 8 KB panel into LDS: 8 dma16 instrs, 2 per wave, lane-contiguous
__device__ __forceinline__ void stage_panel(const _Float16* __restrict__ p,
                                            _Float16* dst, int w, int lane)
{
    #pragma unroll
    for (int ii = 0; ii < 2; ++ii) {
        const int I = 2 * w + ii;           // 0..7 (wave-uniform)
        dma16(p + (size_t)I * 512 + lane * 8, dst + (size_t)I * 512);
    }
}

// one BK=32 compute step: 4x4 fragment tile per wave, single fp16 product
__device__ __forceinline__ void mfma_tile(const _Float16* sA, const _Float16* sB,
                                          int wm, int wn, int kq, int lm,
                                          f32x4 (&acc)[4][4])
{
    f16x8 a[4];
    #pragma unroll
    for (int fm = 0; fm < 4; ++fm)
        a[fm] = *(const f16x8*)(sA + (kq * 128 + wm * 64 + fm * 16 + lm) * 8);
    #pragma unroll
    for (int fn = 0; fn < 4; ++fn) {
        const f16x8 b = *(const f16x8*)(sB + (kq * 128 + wn * 64 + fn * 16 + lm) * 8);
        #pragma unroll
        for (int fm = 0; fm < 4; ++fm)
            acc[fm][fn] = __builtin_amdgcn_mfma_f32_16x16x32_f16(a[fm], b, acc[fm][fn], 0, 0, 0);
    }
}

// bijective XCD swizzle (nwg % 8 == 0): consecutive logical ids -> same XCD L2
__device__ __forceinline__ int xcd_swz(int bid, int nwg) {
    const int q = nwg >> 3;
    return (bid & 7) * q + (bid >> 3);
}

// ---------------------------------------------------------------------------
// prep: codebook -> packed fp16 panels (B-side) + fp32 transposed copy
// (for coalesced fixup distance reads), exact per-code norms, zero accums.
// ---------------------------------------------------------------------------
__global__ __launch_bounds__(256)
void prep_cb_kernel(const float* __restrict__ cb, _Float16* __restrict__ cbP,
                    float* __restrict__ cbT,
                    float* __restrict__ cbnorm, float* __restrict__ accum,
                    int* __restrict__ cnt)
{
    const int j = blockIdx.x;      // code 0..127
    const int t = threadIdx.x;     // dim 0..255
    const float v = cb[j * D_CODE_ + t];
    const int ks = t >> 5, kq = (t >> 3) & 3, jj = t & 7;
    cbP[((size_t)ks * 512 + kq * 128 + j) * 8 + jj] = (_Float16)v;
    cbT[(size_t)t * N_CODES_ + j] = v;

    __shared__ float sr[256];
    sr[t] = v * v;
    __syncthreads();
    for (int s = 128; s >= 1; s >>= 1) {
        if (t < s) sr[t] += sr[t + s];
        __syncthreads();
    }
    if (t == 0) cbnorm[j] = sr[0];
    if (j == 0 && t < 2) accum[t] = 0.0f;
    if (j == 0 && t == 2) *cnt = 0;
}

// ---------------------------------------------------------------------------
// pack_w: W [K][N] fp32 -> B-side panels (n-tiles of 128, k-steps of 32).
// ---------------------------------------------------------------------------
__global__ __launch_bounds__(256)
void pack_w_kernel(const float* __restrict__ W, _Float16* __restrict__ WP,
                   int Kd, int Nd)
{
    const int ks = blockIdx.x, nt = blockIdx.y;
    const int t = threadIdx.x;
    _Float16* dst = WP + ((size_t)nt * (Kd >> 5) + ks) * 4096;
    #pragma unroll
    for (int half = 0; half < 2; ++half) {
        const int f = half * 256 + t;
        const int nc = f & 127, kq = f >> 7;
        f16x8 v;
        #pragma unroll
        for (int j = 0; j < 8; ++j)
            v[j] = (_Float16)W[(size_t)(ks * 32 + kq * 8 + j) * Nd + nt * 128 + nc];
        *(f16x8*)(dst + (size_t)f * 8) = v;
    }
}

// ---------------------------------------------------------------------------
// pack_x: x fp32 [M][1024] -> A-side fp16 panels.  Coalesced reads,
// LDS-tiled, contiguous panel writes.  grid = (M/128, 8).
// ---------------------------------------------------------------------------
__global__ __launch_bounds__(256)
void pack_x_kernel(const float* __restrict__ X, _Float16* __restrict__ XP)
{
    __shared__ _Float16 sh[128][136];   // 272 B rows: 16B-aligned frag reads
    const int t  = threadIdx.x;
    const int mt = blockIdx.x;          // m-tile
    const int kc = blockIdx.y;          // 128-wide k chunk (4 k-steps)

    const float* src = X + (size_t)mt * 128 * D_INK + kc * 128;
    #pragma unroll
    for (int i = 0; i < 16; ++i) {
        const int idx = i * 256 + t;           // 0..4095
        const int row = idx >> 5, c4 = idx & 31;
        const float4 v = *(const float4*)(src + (size_t)row * D_INK + c4 * 4);
        _Float16* d = &sh[row][c4 * 4];
        d[0] = (_Float16)v.x; d[1] = (_Float16)v.y;
        d[2] = (_Float16)v.z; d[3] = (_Float16)v.w;
    }
    __syncthreads();

    _Float16* dst = XP + ((size_t)mt * 32 + kc * 4) * 4096;
    #pragma unroll
    for (int s = 0; s < 4; ++s) {
        #pragma unroll
        for (int half = 0; half < 2; ++half) {
            const int f = half * 256 + t;
            const int rc = f & 127, kq = f >> 7;
            const f16x8 v = *(const f16x8*)(&sh[rc][s * 32 + kq * 8]);
            *(f16x8*)(dst + (size_t)s * 4096 + (size_t)f * 8) = v;
        }
    }
}

// ---------------------------------------------------------------------------
// GEMM1: h = relu(x @ W1 + b1).  All-packed-DMA staging, dbuf LDS (32 KB),
// one __syncthreads per K-step, 4 blocks/CU, XCD-swizzled n-fast grid.
// Output written directly in gemm2's packed-A layout.
// ---------------------------------------------------------------------------
__global__ __launch_bounds__(256, 4)
void gemm1_kernel(const _Float16* __restrict__ AP, const _Float16* __restrict__ BP,
                  const float* __restrict__ bias, _Float16* __restrict__ CP)
{
    __shared__ _Float16 lds[2][2][4096];   // [buf][A,B]  32 KB

    const int tid  = threadIdx.x;
    const int lane = tid & 63;
    const int w    = tid >> 6;
    const int wm = w >> 1, wn = w & 1;
    const int kq = lane >> 4, lm = lane & 15;

    const int swz = xcd_swz(blockIdx.x, (M_ROWS / 128) * (D_HID / 128));
    const int n0 = (swz & 3) * 128;
    const int m0 = (swz >> 2) * 128;

    const _Float16* Apan = AP + ((size_t)(m0 >> 7) * 32) * 4096;
    const _Float16* Bpan = BP + ((size_t)(n0 >> 7) * 32) * 4096;

    f32x4 acc[4][4] = {};

    stage_panel(Apan, &lds[0][0][0], w, lane);
    stage_panel(Bpan, &lds[0][1][0], w, lane);

    constexpr int NSTEP = D_INK / 32;
    for (int t = 0; t < NSTEP; ++t) {
        const int cur = t & 1, nxt = cur ^ 1;
        __syncthreads();               // buf[cur] staged & visible, buf[nxt] free
        if (t + 1 < NSTEP) {
            stage_panel(Apan + (size_t)(t + 1) * 4096, &lds[nxt][0][0], w, lane);
            stage_panel(Bpan + (size_t)(t + 1) * 4096, &lds[nxt][1][0], w, lane);
        }
        mfma_tile(&lds[cur][0][0], &lds[cur][1][0], wm, wn, kq, lm, acc);
    }

    // epilogue: relu; write in gemm2-packed-A layout (NT=16 over D_HID)
    #pragma unroll
    for (int fn = 0; fn < 4; ++fn) {
        const int col = n0 + wn * 64 + fn * 16 + lm;
        const float bv = bias[col];
        #pragma unroll
        for (int fm = 0; fm < 4; ++fm) {
            #pragma unroll
            for (int r = 0; r < 4; ++r) {
                const int row = m0 + wm * 64 + fm * 16 + kq * 4 + r;
                const float v = fmaxf(acc[fm][fn][r] + bv, 0.0f);
                CP[(((size_t)(row >> 7) * 16 + (col >> 5)) * 512
                    + (size_t)((col >> 3) & 3) * 128 + (row & 127)) * 8 + (col & 7)]
                    = (_Float16)v;
            }
        }
    }
}

// ---------------------------------------------------------------------------
// GEMM2: enc = h @ W2 + b2 (+ sum(enc^2) atomic).  Packed in, packed out.
// ---------------------------------------------------------------------------
__global__ __launch_bounds__(256, 4)
void gemm2_kernel(const _Float16* __restrict__ AP, const _Float16* __restrict__ BP,
                  const float* __restrict__ bias, _Float16* __restrict__ CP,
                  float* __restrict__ accum)
{
    __shared__ _Float16 lds[2][2][4096];

    const int tid  = threadIdx.x;
    const int lane = tid & 63;
    const int w    = tid >> 6;
    const int wm = w >> 1, wn = w & 1;
    const int kq = lane >> 4, lm = lane & 15;

    const int swz = xcd_swz(blockIdx.x, (M_ROWS / 128) * (D_CODE_ / 128));
    const int n0 = (swz & 1) * 128;
    const int m0 = (swz >> 1) * 128;

    const _Float16* Apan = AP + ((size_t)(m0 >> 7) * 16) * 4096;
    const _Float16* Bpan = BP + ((size_t)(n0 >> 7) * 16) * 4096;

    f32x4 acc[4][4] = {};

    stage_panel(Apan, &lds[0][0][0], w, lane);
    stage_panel(Bpan, &lds[0][1][0], w, lane);

    constexpr int NSTEP = D_HID / 32;
    for (int t = 0; t < NSTEP; ++t) {
        const int cur = t & 1, nxt = cur ^ 1;
        __syncthreads();
        if (t + 1 < NSTEP) {
            stage_panel(Apan + (size_t)(t + 1) * 4096, &lds[nxt][0][0], w, lane);
            stage_panel(Bpan + (size_t)(t + 1) * 4096, &lds[nxt][1][0], w, lane);
        }
        mfma_tile(&lds[cur][0][0], &lds[cur][1][0], wm, wn, kq, lm, acc);
    }

    float sumsq = 0.0f;
    #pragma unroll
    for (int fn = 0; fn < 4; ++fn) {
        const int col = n0 + wn * 64 + fn * 16 + lm;
        const float bv = bias[col];
        #pragma unroll
        for (int fm = 0; fm < 4; ++fm) {
            #pragma unroll
            for (int r = 0; r < 4; ++r) {
                const int row = m0 + wm * 64 + fm * 16 + kq * 4 + r;
                const float v = acc[fm][fn][r] + bv;
                sumsq = fmaf(v, v, sumsq);
                CP[(((size_t)(row >> 7) * 8 + (col >> 5)) * 512
                    + (size_t)((col >> 3) & 3) * 128 + (row & 127)) * 8 + (col & 7)]
                    = (_Float16)v;
            }
        }
    }
    #pragma unroll
    for (int mk = 1; mk <= 32; mk <<= 1) sumsq += __shfl_xor(sumsq, mk);
    if (lane == 0) atomicAdd(&accum[1], sumsq);
}

// ---------------------------------------------------------------------------
// dist: dots = enc @ cb^T (one n-block = all 128 codes); argmin epilogue
// with second-best gap flagging + min-term loss sum.
// ---------------------------------------------------------------------------
__global__ __launch_bounds__(256, 4)
void dist_kernel(const _Float16* __restrict__ AP, const _Float16* __restrict__ BP,
                 const float* __restrict__ cbn,
                 float* __restrict__ outIdx, float* __restrict__ accum,
                 int* __restrict__ cnt, int* __restrict__ list)
{
    __shared__ _Float16 lds[2][2][4096];

    const int tid  = threadIdx.x;
    const int lane = tid & 63;
    const int w    = tid >> 6;
    const int wm = w >> 1, wn = w & 1;
    const int kq = lane >> 4, lm = lane & 15;
    const int m0 = blockIdx.x * 128;

    float cbn_l[4];
    #pragma unroll
    for (int fn = 0; fn < 4; ++fn) cbn_l[fn] = cbn[wn * 64 + fn * 16 + lm];

    const _Float16* Apan = AP + ((size_t)(m0 >> 7) * 8) * 4096;

    f32x4 acc[4][4] = {};

    stage_panel(Apan, &lds[0][0][0], w, lane);
    stage_panel(BP,   &lds[0][1][0], w, lane);

    constexpr int NSTEP = D_CODE_ / 32;
    for (int t = 0; t < NSTEP; ++t) {
        const int cur = t & 1, nxt = cur ^ 1;
        __syncthreads();
        if (t + 1 < NSTEP) {
            stage_panel(Apan + (size_t)(t + 1) * 4096, &lds[nxt][0][0], w, lane);
            stage_panel(BP   + (size_t)(t + 1) * 4096, &lds[nxt][1][0], w, lane);
        }
        mfma_tile(&lds[cur][0][0], &lds[cur][1][0], wm, wn, kq, lm, acc);
    }

    __syncthreads();   // all LDS reads done before reuse as epilogue scratch
    float* eb1 = (float*)&lds[0][0][0];        // [2][128]
    float* eb2 = eb1 + 256;
    int*   eix = (int*)(eb2 + 256);

    #pragma unroll
    for (int fm = 0; fm < 4; ++fm) {
        #pragma unroll
        for (int r = 0; r < 4; ++r) {
            float b1v = 3.4e38f, b2v = 3.4e38f; int bi = 0;
            #pragma unroll
            for (int fn = 0; fn < 4; ++fn) {
                const float v = fmaf(-2.0f, acc[fm][fn][r], cbn_l[fn]);
                if (v < b1v) { b2v = b1v; b1v = v; bi = wn * 64 + fn * 16 + lm; }
                else if (v < b2v) b2v = v;
            }
            #pragma unroll
            for (int mk = 1; mk <= 8; mk <<= 1) {
                const float o1 = __shfl_xor(b1v, mk);
                const float o2 = __shfl_xor(b2v, mk);
                const int   oi = __shfl_xor(bi,  mk);
                if (o1 < b1v || (o1 == b1v && oi < bi)) { b2v = fminf(b1v, o2); b1v = o1; bi = oi; }
                else b2v = fminf(b2v, o1);
            }
            const int rl = wm * 64 + fm * 16 + kq * 4 + r;
            if (lm == 0) { eb1[wn * 128 + rl] = b1v; eb2[wn * 128 + rl] = b2v; eix[wn * 128 + rl] = bi; }
        }
    }
    __syncthreads();

    if (tid < 128) {
        const int rl = tid;
        const float a1 = eb1[rl], a2 = eb2[rl]; const int ai = eix[rl];
        const float o1 = eb1[128 + rl], o2 = eb2[128 + rl]; const int oi = eix[128 + rl];
        float B1, B2; int BI;
        if (o1 < a1 || (o1 == a1 && oi < ai)) { B1 = o1; BI = oi; B2 = fminf(a1, o2); }
        else                                  { B1 = a1; BI = ai; B2 = fminf(a2, o1); }
        outIdx[m0 + rl] = (float)BI;
        if (B2 - B1 < TAU_GAP) { const int p = atomicAdd(cnt, 1); list[p] = m0 + rl; }
        float s = B1;
        #pragma unroll
        for (int mk = 1; mk <= 32; mk <<= 1) s += __shfl_xor(s, mk);
        if (lane == 0) atomicAdd(&accum[0], s);
    }
}

// ---------------------------------------------------------------------------
// fixup: exact fp32 recompute of flagged rows, batched 8 rows per group.
// x/h/enc broadcasts via v_readlane from per-lane register chunks (zero
// LDS-pipe pressure in the hot loops); W1/W2/cbT reads lane-coalesced.
// ---------------------------------------------------------------------------
__global__ __launch_bounds__(256)
void fixup_kernel(const float* __restrict__ x, const float* __restrict__ W1,
                  const float* __restrict__ b1, const float* __restrict__ W2,
                  const float* __restrict__ b2, const float* __restrict__ cbT,
                  const float* __restrict__ cbnorm,
                  const int* __restrict__ cnt, const int* __restrict__ list,
                  float* __restrict__ outIdx)
{
    __shared__ float xr[8][1024];   // 32 KB
    __shared__ float hr[8][512];    // 16 KB
    __shared__ float er[8][256];    //  8 KB
    __shared__ float dv[8][128];    //  4 KB
    __shared__ int   di[8][128];    //  4 KB

    const int tid  = threadIdx.x;
    const int lane = tid & 63;
    const int n = *cnt;
    const int ngroups = (n + 7) >> 3;

    for (int g = blockIdx.x; g < ngroups; g += gridDim.x) {
        const int base = g * 8;
        const int nr = n - base < 8 ? n - base : 8;
        __syncthreads();   // LDS reuse guard across group iterations
        #pragma unroll
        for (int r = 0; r < 8; ++r) {
            if (r < nr) {
                const int row = list[base + r];
                *(float4*)&xr[r][tid * 4] =
                    *(const float4*)(x + (size_t)row * D_INK + tid * 4);
            }
        }
        __syncthreads();

        // h = relu(x @ W1 + b1): thread owns cols (2t, 2t+1), all 8 rows.
        {
            const int c = tid * 2;
            float a0[8], a1[8];
            #pragma unroll
            for (int r = 0; r < 8; ++r) { a0[r] = 0.f; a1[r] = 0.f; }
            for (int k0 = 0; k0 < D_INK; k0 += 64) {
                float xreg[8];
                #pragma unroll
                for (int r = 0; r < 8; ++r) xreg[r] = xr[r][k0 + lane];
                #pragma unroll 8
                for (int kk = 0; kk < 64; ++kk) {
                    const float2 wv = *(const float2*)(W1 + (size_t)(k0 + kk) * D_HID + c);
                    #pragma unroll
                    for (int r = 0; r < 8; ++r) {
                        const float xv = rdlane(xreg[r], kk);
                        a0[r] = fmaf(xv, wv.x, a0[r]);
                        a1[r] = fmaf(xv, wv.y, a1[r]);
                    }
                }
            }
            #pragma unroll
            for (int r = 0; r < 8; ++r) {
                hr[r][c]     = fmaxf(a0[r] + b1[c], 0.f);
                hr[r][c + 1] = fmaxf(a1[r] + b1[c + 1], 0.f);
            }
        }
        __syncthreads();

        // enc = h @ W2 + b2: thread owns col tid, all 8 rows.
        {
            float a[8];
            #pragma unroll
            for (int r = 0; r < 8; ++r) a[r] = 0.f;
            for (int k0 = 0; k0 < D_HID; k0 += 64) {
                float hreg[8];
                #pragma unroll
                for (int r = 0; r < 8; ++r) hreg[r] = hr[r][k0 + lane];
                #pragma unroll 8
                for (int kk = 0; kk < 64; ++kk) {
                    const float wv = W2[(size_t)(k0 + kk) * D_CODE_ + tid];
                    #pragma unroll
                    for (int r = 0; r < 8; ++r)
                        a[r] = fmaf(rdlane(hreg[r], kk), wv, a[r]);
                }
            }
            #pragma unroll
            for (int r = 0; r < 8; ++r)
                er[r][tid] = a[r] + b2[tid];
        }
        __syncthreads();

        // distances (reference expanded form): thread (j = tid&127,
        // half = tid>>7) handles rows half*4..+3; cbT lane-coalesced.
        {
            const int j = tid & 127, half = tid >> 7;
            float e2[4], dt[4];
            #pragma unroll
            for (int q = 0; q < 4; ++q) { e2[q] = 0.f; dt[q] = 0.f; }
            for (int k0 = 0; k0 < D_CODE_; k0 += 64) {
                float ereg[4];
                #pragma unroll
                for (int q = 0; q < 4; ++q) ereg[q] = er[half * 4 + q][k0 + lane];
                #pragma unroll 8
                for (int kk = 0; kk < 64; ++kk) {
                    const float cv = cbT[(size_t)(k0 + kk) * N_CODES_ + j];
                    #pragma unroll
                    for (int q = 0; q < 4; ++q) {
                        const float ev = rdlane(ereg[q], kk);
                        e2[q] = fmaf(ev, ev, e2[q]);
                        dt[q] = fmaf(ev, cv, dt[q]);
                    }
                }
            }
            #pragma unroll
            for (int q = 0; q < 4; ++q) {
                dv[half * 4 + q][j] = (e2[q] - 2.0f * dt[q]) + cbnorm[j];
                di[half * 4 + q][j] = j;
            }
        }
        __syncthreads();

        // argmin reduce: 2 passes x 4 rows, 64 threads per row
        #pragma unroll
        for (int pass = 0; pass < 2; ++pass) {
            const int r = pass * 4 + (tid >> 6);
            const int i = tid & 63;
            {   // st = 64: partner index i+64 > i, so ties keep lower index
                const float a = dv[r][i], b = dv[r][i + 64];
                const int  ib = di[r][i + 64];
                if (b < a) { dv[r][i] = b; di[r][i] = ib; }
            }
            __syncthreads();
            for (int st = 32; st >= 1; st >>= 1) {
                if (i < st) {
                    const float a = dv[r][i], b = dv[r][i + st];
                    const int  ib = di[r][i + st];
                    if (b < a || (b == a && ib < di[r][i])) { dv[r][i] = b; di[r][i] = ib; }
                }
                __syncthreads();
            }
        }
        if (tid < nr) outIdx[list[base + tid]] = (float)di[tid][0];
    }
}

// ---------------------------------------------------------------------------
__global__ void finalize_kernel(const float* __restrict__ accum, float* __restrict__ out)
{
    const float inv = 1.0f / (32768.0f * 256.0f);
    const float loss = (accum[0] + accum[1]) * inv;   // commitment == codebook
    out[32768] = loss;
    out[32769] = loss;
    out[32770] = 1.25f * loss;
}

// ---------------------------------------------------------------------------
extern "C" void kernel_launch(void* const* d_in, const int* in_sizes, int n_in,
                              void* d_out, int out_size, void* d_ws, size_t ws_size,
                              hipStream_t stream)
{
    (void)in_sizes; (void)n_in; (void)out_size; (void)ws_size;

    const float* x  = (const float*)d_in[0];  // [32768,1024]
    const float* W1 = (const float*)d_in[1];  // [1024,512]
    const float* b1 = (const float*)d_in[2];  // [512]
    const float* W2 = (const float*)d_in[3];  // [512,256]
    const float* b2 = (const float*)d_in[4];  // [256]
    const float* cb = (const float*)d_in[5];  // [128,256]
    float* out = (float*)d_out;

    // workspace layout (bytes); encP overlaps xP (xP dead after gemm1)
    char* ws = (char*)d_ws;
    _Float16* W1P  = (_Float16*)(ws + 0);                 // 1 MB   (4 nt x 32 ks)
    _Float16* W2P  = (_Float16*)(ws + 1048576);           // 256 KB (2 nt x 16 ks)
    _Float16* cbP  = (_Float16*)(ws + 1310720);           // 64 KB  (1 nt x 8 ks)
    float*    cbn  = (float*   )(ws + 1376256);           // 512 B
    float*    accum= (float*   )(ws + 1376768);           // 64 B
    int*      cnt  = (int*     )(ws + 1376832);           // 64 B
    int*      list = (int*     )(ws + 1376896);           // 128 KB
    float*    cbT  = (float*   )(ws + 1507968);           // 128 KB fp32 [256][128]
    _Float16* xP   = (_Float16*)(ws + (size_t)(2u<<20));              // 64 MB
    _Float16* encP = (_Float16*)(ws + (size_t)(2u<<20));              // 16 MB (reuse)
    _Float16* hP   = (_Float16*)(ws + (size_t)(2u<<20) + 67108864);   // 32 MB

    prep_cb_kernel<<<N_CODES_, 256, 0, stream>>>(cb, cbP, cbT, cbn, accum, cnt);
    pack_w_kernel<<<dim3(D_INK / 32, D_HID / 128), 256, 0, stream>>>(W1, W1P, D_INK, D_HID);
    pack_w_kernel<<<dim3(D_HID / 32, D_CODE_ / 128), 256, 0, stream>>>(W2, W2P, D_HID, D_CODE_);
    pack_x_kernel<<<dim3(M_ROWS / 128, D_INK / 128), 256, 0, stream>>>(x, xP);

    gemm1_kernel<<<(M_ROWS / 128) * (D_HID / 128), 256, 0, stream>>>(xP, W1P, b1, hP);
    gemm2_kernel<<<(M_ROWS / 128) * (D_CODE_ / 128), 256, 0, stream>>>(hP, W2P, b2, encP, accum);
    dist_kernel<<<M_ROWS / 128, 256, 0, stream>>>(encP, cbP, cbn, out, accum, cnt, list);
    fixup_kernel<<<512, 256, 0, stream>>>(x, W1, b1, W2, b2, cbT, cbn, cnt, list, out);
    finalize_kernel<<<1, 1, 0, stream>>>(accum, out);
}